// Round 9
// baseline (6815.043 us; speedup 1.0000x reference)
//
#include <hip/hip_runtime.h>

typedef __attribute__((ext_vector_type(8))) short short8;
typedef __attribute__((ext_vector_type(4))) float f32x4;

#define B_   64
#define S_   512
#define V_   1400
#define VP_  1408
#define H_   256
#define G4_  1024
#define NC_  128
#define CH_  64    // time-chunk length (8 chunks of 64 steps)

__device__ __forceinline__ unsigned short f2bf(float f) {
    unsigned u = __builtin_bit_cast(unsigned, f);
    u += 0x7FFFu + ((u >> 16) & 1u);
    return (unsigned short)(u >> 16);
}
__device__ __forceinline__ float bf2f(unsigned short h) {
    unsigned u = ((unsigned)h) << 16;
    return __builtin_bit_cast(float, u);
}
__device__ __forceinline__ float fsig(float x) {
    x = fminf(fmaxf(x, -40.f), 40.f);
    float e = __builtin_amdgcn_exp2f(x * -1.44269504f);
    return __builtin_amdgcn_rcpf(1.0f + e);
}
__device__ __forceinline__ float ftanh(float x) {
    x = fminf(fmaxf(x, -40.f), 40.f);
    float e = __builtin_amdgcn_exp2f(x * 2.88539008f);
    return 1.0f - 2.0f * __builtin_amdgcn_rcpf(e + 1.0f);
}

// ---- IC-coherent (cross-XCD) data primitives — proven ----
__device__ __forceinline__ short8 gload16_sc1(const unsigned short* p) {
    short8 r;
    asm volatile("global_load_dwordx4 %0, %1, off sc1"
                 : "=&v"(r) : "v"((unsigned long long)p));
    return r;
}
__device__ __forceinline__ void gstore_short_sc1(unsigned short* p, unsigned v) {
    asm volatile("global_store_short %0, %1, off sc1"
                 :: "v"((unsigned long long)p), "v"(v));
}
// ---- L2-local (same-XCD) data primitives — proven ----
__device__ __forceinline__ short8 gload16_sc0(const unsigned short* p) {
    short8 r;
    asm volatile("global_load_dwordx4 %0, %1, off sc0"
                 : "=&v"(r) : "v"((unsigned long long)p));
    return r;
}
__device__ __forceinline__ void gstore_short_plain(unsigned short* p, unsigned v) {
    asm volatile("global_store_short %0, %1, off"
                 :: "v"((unsigned long long)p), "v"(v));
}

// cnt zone layout (ints): pair counters ((chunk*8+grp)*2+half)*64  [0,8192)
//                         rdy[chunk] at 8192+chunk*64              [8192,8704)
//                         xpub[16]   at 8704                       [8704,8720)
#define CNT_ZONE_ 9216

// ---------------------------------------------------------------- K0: prep
__global__ void k0_prep(const float* __restrict__ emb,
                        const float* __restrict__ Wa1, const float* __restrict__ Wa2,
                        const float* __restrict__ Wd1, const float* __restrict__ Wd2,
                        const float* __restrict__ U1,  const float* __restrict__ U2,
                        const float* __restrict__ ba1, const float* __restrict__ bu1,
                        const float* __restrict__ ba2, const float* __restrict__ bu2,
                        const float* __restrict__ Wb,
                        unsigned short* __restrict__ embT, unsigned short* __restrict__ Wg,
                        unsigned short* __restrict__ Wd,   unsigned short* __restrict__ Ub,
                        unsigned short* __restrict__ Wbb,  float* __restrict__ bg,
                        unsigned int* __restrict__ cnt) {
    int tid = blockIdx.x * blockDim.x + threadIdx.x;
    int np = gridDim.x * blockDim.x;
    for (int i = tid; i < 256 * VP_; i += np) {
        int n = i / VP_, k = i - n * VP_;
        embT[i] = (k < V_) ? f2bf(emb[k * H_ + n]) : (unsigned short)0;
    }
    for (int i = tid; i < G4_ * H_; i += np) {
        Wg[i] = f2bf(Wa1[i]); Wg[G4_ * H_ + i] = f2bf(Wa2[i]);
        Ub[i] = f2bf(U1[i]);  Ub[G4_ * H_ + i] = f2bf(U2[i]);
    }
    for (int i = tid; i < H_ * H_; i += np) {
        Wd[i] = f2bf(Wd1[i]); Wd[H_ * H_ + i] = f2bf(Wd2[i]); Wbb[i] = f2bf(Wb[i]);
    }
    for (int i = tid; i < G4_; i += np) {
        bg[i] = ba1[i] + bu1[i]; bg[G4_ + i] = ba2[i] + bu2[i];
    }
    for (int i = tid; i < CNT_ZONE_; i += np) cnt[i] = 0;   // sync zone (re-zeroed every run)
}

// ---------------------------------------------------------------- K1: embedded = inputs @ emb
__global__ __launch_bounds__(512, 2) void k1_embed(const float* __restrict__ inputs,
                                                   const unsigned short* __restrict__ embT,
                                                   unsigned short* __restrict__ embB) {
    const int tid = threadIdx.x;
    const int w = tid >> 6, ln = tid & 63, q = ln >> 4, l16 = ln & 15;
    const int mt = w >> 2, ng = (w & 3) * 4;
    const int Rbase = blockIdx.x * 32 + mt * 16;
    const float* arow = inputs + (long)(Rbase + l16) * V_;

    f32x4 acc[4];
    #pragma unroll
    for (int i = 0; i < 4; ++i) acc[i] = (f32x4){0.f, 0.f, 0.f, 0.f};

    for (int kt = 0; kt < 44; ++kt) {
        int k0 = kt * 32 + q * 8;
        short8 af;
        if (kt == 43 && q == 3) {
            #pragma unroll
            for (int j = 0; j < 8; ++j) af[j] = 0;
        } else {
            f32x4 x0 = *(const f32x4*)(arow + k0);
            f32x4 x1 = *(const f32x4*)(arow + k0 + 4);
            #pragma unroll
            for (int j = 0; j < 4; ++j) { af[j] = (short)f2bf(x0[j]); af[4 + j] = (short)f2bf(x1[j]); }
        }
        #pragma unroll
        for (int i = 0; i < 4; ++i) {
            short8 bf = *(const short8*)(embT + (long)((ng + i) * 16 + l16) * VP_ + k0);
            acc[i] = __builtin_amdgcn_mfma_f32_16x16x32_bf16(af, bf, acc[i], 0, 0, 0);
        }
    }
    #pragma unroll
    for (int i = 0; i < 4; ++i) {
        int col = (ng + i) * 16 + l16;
        #pragma unroll
        for (int j = 0; j < 4; ++j) {
            int R = Rbase + 4 * q + j;
            embB[(long)R * H_ + col] = f2bf(acc[i][j]);
        }
    }
}

// ---------------------------------------------------------------- K2: P chunk = embedded @ [U1;U2]^T + bg
// (chunk-0 prologue and no-fuse fallback)
__global__ __launch_bounds__(512, 2) void k2_pre(const unsigned short* __restrict__ embB,
                                                 const unsigned short* __restrict__ Ub,
                                                 const float* __restrict__ bg,
                                                 float* __restrict__ P, int t0) {
    const int tid = threadIdx.x;
    const int w = tid >> 6, ln = tid & 63, q = ln >> 4, l16 = ln & 15;
    const int rbase = blockIdx.x * 32;  // local row' in chunk, 0..4095

    short8 af[2][8];
    #pragma unroll
    for (int mt = 0; mt < 2; ++mt)
        #pragma unroll
        for (int kt = 0; kt < 8; ++kt) {
            int rp = rbase + mt * 16 + l16;
            int rg = t0 * 64 + rp;
            int b = rg & 63, s = rg >> 6;
            af[mt][kt] = *(const short8*)(embB + ((long)b * S_ + s) * H_ + kt * 32 + q * 8);
        }

    for (int i = 0; i < 16; ++i) {
        int nt2 = w * 16 + i;          // global gate-col tile 0..127
        int l = nt2 >> 6;
        int gcol = (nt2 & 63) * 16 + l16;   // col within lstm, 0..1023
        float bias = bg[nt2 * 16 + l16];
        short8 bf[8];
        #pragma unroll
        for (int kt = 0; kt < 8; ++kt)
            bf[kt] = *(const short8*)(Ub + (long)(nt2 * 16 + l16) * H_ + kt * 32 + q * 8);
        #pragma unroll
        for (int mt = 0; mt < 2; ++mt) {
            f32x4 acc = (f32x4){bias, bias, bias, bias};
            #pragma unroll
            for (int kt = 0; kt < 8; ++kt)
                acc = __builtin_amdgcn_mfma_f32_16x16x32_bf16(af[mt][kt], bf[kt], acc, 0, 0, 0);
            int rp0 = rbase + mt * 16;
            float* dst = P + ((long)l * (CH_ * 64) + rp0 + 4 * q) * G4_ + gcol;
            #pragma unroll
            for (int j = 0; j < 4; ++j) dst[(long)j * G4_] = acc[j];
        }
    }
}

// ---------------------------------------------------------------- K3: fused LSTM chunk + next-chunk P GEMM
// Round-14 restructure: 2-block PAIR groups with a block-local K half.
//   8 rounds bracketed the 4-way rendezvous at ~3.5-4us/step regardless of
//   detection primitive (r2 257 / r6 270 / r7 273 / r8 300us) while compute is
//   ~0.25us -> change the STRUCTURE, not the primitive:
//   - 16 LSTM blocks; each owns 128 hidden cols (32/wave). Own h/c half lives
//     in LDS -> half the per-step K needs NO fabric. Local 40 MFMAs + all LDS
//     reads run DURING the peer wait (before vmcnt(0)).
//   - 1-peer rendezvous (was max-of-3): less skew, less counter contention.
//   - pv loads issued alongside the gathers, consumed after the same vmcnt(0)
//     (kills r8's fence-drains-prefetch hazard by construction).
//   - wg register/AGPR-resident (256 regs = the AGPR file); Wd moved to LDS
//     (66KB) to fit the unified budget.
//   Sync: r6/r2-proven primitives only. Post = AGENT fetch_add after data
//   drain; poll = lane0 AGENT RMW fetch_add(opaque 0) + shfl, bounded.
//   Data scope: pair same-XCD (checked) -> plain stores + sc0 loads + per-step
//   acquire fence; else sc1 both sides (no fence needed). Numerics identical.
__global__ __launch_bounds__(256, 1) void k3_fused(const float* __restrict__ ts,
                                                   const unsigned short* __restrict__ W, // Wg || Wd
                                                   const float* __restrict__ bd1,
                                                   const float* __restrict__ bd2,
                                                   const float* __restrict__ Pcur,
                                                   unsigned short* __restrict__ out1,
                                                   unsigned short* __restrict__ out2,
                                                   float* __restrict__ cst,
                                                   unsigned short* __restrict__ cx,
                                                   unsigned int* __restrict__ cnt,
                                                   int t0,
                                                   const unsigned short* __restrict__ embB,
                                                   const unsigned short* __restrict__ Ub,
                                                   const float* __restrict__ bg,
                                                   float* __restrict__ Pnext,
                                                   int next_t0) {
    const int tid = threadIdx.x;
    const int w = tid >> 6, ln = tid & 63, q = ln >> 4, l16 = ln & 15;
    const int bid = blockIdx.x;

    if (bid >= 16) {
        // ================= GEMM role: P(next chunk) = embB @ Ub^T + bg =======
        const int g2 = bid - 16;
        const int rbase = (g2 >> 1) * 32;
        const int hb = g2 & 1;

        short8 af[2][8];
        #pragma unroll
        for (int mt = 0; mt < 2; ++mt)
            #pragma unroll
            for (int kt = 0; kt < 8; ++kt) {
                int rp = rbase + mt * 16 + l16;
                int rg = next_t0 * 64 + rp;
                int b = rg & 63, s = rg >> 6;
                af[mt][kt] = *(const short8*)(embB + ((long)b * S_ + s) * H_ + kt * 32 + q * 8);
            }

        for (int i = 0; i < 16; ++i) {
            int nt2 = hb * 64 + w * 16 + i;
            int l = nt2 >> 6;
            int gcol = (nt2 & 63) * 16 + l16;
            float bias = bg[nt2 * 16 + l16];
            short8 bf[8];
            #pragma unroll
            for (int kt = 0; kt < 8; ++kt)
                bf[kt] = *(const short8*)(Ub + (long)(nt2 * 16 + l16) * H_ + kt * 32 + q * 8);
            #pragma unroll
            for (int mt = 0; mt < 2; ++mt) {
                f32x4 acc = (f32x4){bias, bias, bias, bias};
                #pragma unroll
                for (int kt = 0; kt < 8; ++kt)
                    acc = __builtin_amdgcn_mfma_f32_16x16x32_bf16(af[mt][kt], bf[kt], acc, 0, 0, 0);
                int rp0 = rbase + mt * 16;
                float* dst = Pnext + ((long)l * (CH_ * 64) + rp0 + 4 * q) * G4_ + gcol;
                #pragma unroll
                for (int j = 0; j < 4; ++j) dst[(long)j * G4_] = acc[j];
            }
        }
        return;
    }

    // ==================== LSTM role (blocks 0..15) ===========================
    __shared__ float ts_lds[16][CH_];                // 4 KB
    __shared__ unsigned short h_loc[16][136];        // 4.25 KB (pad: 2-way banks)
    __shared__ unsigned short c_loc[16][136];        // 4.25 KB
    __shared__ unsigned short wd_lds[128][264];      // 66 KB  (pad: 2-way banks)
    const int chunk = t0 >> 6;

    // -------- XCD discovery (IC-scope handshake, once per launch) ------------
    const int myx = (int)__builtin_amdgcn_s_getreg(63508);  // HW_REG_XCC_ID
    unsigned int* rdy  = cnt + 8192 + chunk * 64;
    int*          xpub = (int*)(cnt + 8704);
    if (tid == 0) {
        __hip_atomic_store(&xpub[bid], myx, __ATOMIC_RELAXED, __HIP_MEMORY_SCOPE_AGENT);
        __hip_atomic_fetch_add(rdy, 1u, __ATOMIC_RELEASE, __HIP_MEMORY_SCOPE_AGENT);
    }
    unsigned hs_it = 0;
    while (__hip_atomic_load(rdy, __ATOMIC_ACQUIRE, __HIP_MEMORY_SCOPE_AGENT) < 16u
           && ++hs_it < (1u << 20))
        __builtin_amdgcn_s_sleep(2);
    int xv[16];
    #pragma unroll
    for (int i = 0; i < 16; ++i)
        xv[i] = __hip_atomic_load(&xpub[i], __ATOMIC_RELAXED, __HIP_MEMORY_SCOPE_AGENT);
    unsigned okP = 1, inr = 1, mask = 0;
    #pragma unroll
    for (int g = 0; g < 8; ++g)
        okP &= (unsigned)(xv[g] == xv[g + 8]);
    #pragma unroll
    for (int i = 0; i < 16; ++i) {
        inr &= (unsigned)((unsigned)xv[i] < 8u);
        mask |= 1u << ((unsigned)xv[i] & 31u);
    }
    const bool fast = okP && inr && (mask == 0xFFu) && (hs_it < (1u << 20));

    // -------- role decode: pair = {grp, grp+8}; half = col half --------------
    const int grp = bid & 7, half = bid >> 3;
    const int l = grp >> 2, m = grp & 3, b0 = m * 16;
    const int colB0 = w * 32;                 // wave's block-local col base (0..96)
    unsigned int* own_cell  = cnt + (((chunk * 8 + grp) * 2) + half) * 64;
    unsigned int* peer_cell = cnt + (((chunk * 8 + grp) * 2) + (half ^ 1)) * 64;
    unsigned short* outp = l ? out2 : out1;
    const float* bdp = l ? bd2 : bd1;
    float bdv[2];
    bdv[0] = bdp[half * 128 + colB0 + l16];
    bdv[1] = bdp[half * 128 + colB0 + 16 + l16];

    for (int i = tid; i < 16 * CH_; i += 256) {
        int r = i >> 6, cc = i & (CH_ - 1);
        ts_lds[r][cc] = ts[(b0 + r) * S_ + t0 + cc];
    }
    // Wd slice -> LDS (rows = block's 128 cols, k = 0..255)
    for (int i = tid; i < 128 * 2; i += 256) {
        int ri = i >> 1, k0 = (i & 1) * 128;
        const unsigned short* src = W + (long)2 * G4_ * H_ + ((long)(l * H_ + half * 128 + ri)) * H_ + k0;
        #pragma unroll
        for (int c8 = 0; c8 < 128; c8 += 8)
            *(short8*)&wd_lds[ri][k0 + c8] = *(const short8*)(src + c8);
    }

    // -------- register/AGPR-resident gate weights (256 regs) -----------------
    short8 wg[4][2][8];
    #pragma unroll
    for (int g = 0; g < 4; ++g)
        #pragma unroll
        for (int ct = 0; ct < 2; ++ct)
            #pragma unroll
            for (int kt = 0; kt < 8; ++kt)
                wg[g][ct][kt] = *(const short8*)(W +
                    ((long)(l * G4_ + g * H_ + half * 128 + colB0 + ct * 16 + l16)) * H_ + kt * 32 + q * 8);

    // -------- local state init ----------------------------------------------
    float cf[2][4];
    if (t0 == 0) {
        #pragma unroll
        for (int ct = 0; ct < 2; ++ct)
            #pragma unroll
            for (int j = 0; j < 4; ++j) cf[ct][j] = 0.f;
        for (int i = tid; i < 16 * 16; i += 256) {
            int r = i >> 4, c8 = (i & 15) * 8;
            short8 z;
            #pragma unroll
            for (int jj = 0; jj < 8; ++jj) z[jj] = 0;
            *(short8*)&h_loc[r][c8] = z;
            *(short8*)&c_loc[r][c8] = z;
        }
    } else {
        #pragma unroll
        for (int ct = 0; ct < 2; ++ct)
            #pragma unroll
            for (int j = 0; j < 4; ++j)
                cf[ct][j] = cst[(long)(l * 4 + m) * 4096 + (4 * q + j) * 256 + half * 128 + colB0 + ct * 16 + l16];
        for (int i = tid; i < 16 * 16; i += 256) {
            int r = i >> 4, c8 = (i & 15) * 8;
            *(short8*)&h_loc[r][c8] =
                *(const short8*)(outp + ((long)(b0 + r) * S_ + (t0 - 1)) * H_ + half * 128 + c8);
            const float* cp = cst + (long)(l * 4 + m) * 4096 + r * 256 + half * 128 + c8;
            short8 cv;
            #pragma unroll
            for (int jj = 0; jj < 8; ++jj) cv[jj] = (short)f2bf(cp[jj]);
            *(short8*)&c_loc[r][c8] = cv;
        }
    }
    __syncthreads();   // LDS (ts, wd, h/c) ready

    const float* Pbase = Pcur + ((long)l * (CH_ * 64) + b0) * G4_;
    unsigned opaque_zero;
    asm volatile("v_mov_b32 %0, 0" : "=v"(opaque_zero));

    #pragma unroll 1
    for (int t = 0; t < CH_; ++t) {
        const int gt = t0 + t;

        // 1. wait for the peer to finish step t-1 (bounded AGENT RMW poll)
        if (t > 0) {
            const unsigned tgt = 4u * (unsigned)t;
            unsigned it = 0;
            for (;;) {
                unsigned v = 0;
                if (ln == 0)
                    v = __hip_atomic_fetch_add(peer_cell, opaque_zero,
                                               __ATOMIC_RELAXED, __HIP_MEMORY_SCOPE_AGENT);
                v = __shfl(v, 0);
                if (v >= tgt || ++it >= (1u << 14)) break;
            }
            if (fast) __builtin_amdgcn_fence(__ATOMIC_ACQUIRE, "agent");  // L1 inv for gathers
        }
        __builtin_amdgcn_sched_barrier(0);

        // 2. issue remote gathers (peer 128-col half) + pv loads
        short8 har[4], car[4];
        if (gt == 0) {
            #pragma unroll
            for (int kt2 = 0; kt2 < 4; ++kt2) {
                #pragma unroll
                for (int jj = 0; jj < 8; ++jj) { har[kt2][jj] = 0; car[kt2][jj] = 0; }
            }
        } else {
            const unsigned short* crow = cx + ((long)(((gt - 1) & 1) * 8 + grp)) * 4096
                                           + l16 * 256 + (half ^ 1) * 128 + q * 8;
            const unsigned short* hrow = outp + ((long)(b0 + l16) * S_ + (gt - 1)) * H_
                                              + (half ^ 1) * 128 + q * 8;
            if (fast) {
                #pragma unroll
                for (int kt2 = 0; kt2 < 4; ++kt2) car[kt2] = gload16_sc0(crow + kt2 * 32);
                #pragma unroll
                for (int kt2 = 0; kt2 < 4; ++kt2) har[kt2] = gload16_sc0(hrow + kt2 * 32);
            } else {
                #pragma unroll
                for (int kt2 = 0; kt2 < 4; ++kt2) car[kt2] = gload16_sc1(crow + kt2 * 32);
                #pragma unroll
                for (int kt2 = 0; kt2 < 4; ++kt2) har[kt2] = gload16_sc1(hrow + kt2 * 32);
            }
        }
        float pv[4][2][4];
        #pragma unroll
        for (int g = 0; g < 4; ++g)
            #pragma unroll
            for (int ct = 0; ct < 2; ++ct)
                #pragma unroll
                for (int j = 0; j < 4; ++j)
                    pv[g][ct][j] = Pbase[((long)t * 64 + 4 * q + j) * G4_
                                         + g * H_ + half * 128 + colB0 + ct * 16 + l16];

        // 3. LOCAL phase (LDS only) — runs while remote loads are in flight
        f32x4 dacc[2];
        dacc[0] = (f32x4){bdv[0], bdv[0], bdv[0], bdv[0]};
        dacc[1] = (f32x4){bdv[1], bdv[1], bdv[1], bdv[1]};
        f32x4 gacc[4][2];
        #pragma unroll
        for (int g = 0; g < 4; ++g)
            #pragma unroll
            for (int ct = 0; ct < 2; ++ct) gacc[g][ct] = (f32x4){0.f, 0.f, 0.f, 0.f};

        if (gt > 0) {
            #pragma unroll
            for (int kt2 = 0; kt2 < 4; ++kt2) {
                const int ktg = half * 4 + kt2;
                short8 cl = *(const short8*)&c_loc[l16][kt2 * 32 + q * 8];
                #pragma unroll
                for (int ct = 0; ct < 2; ++ct) {
                    short8 wdf = *(const short8*)&wd_lds[colB0 + ct * 16 + l16][ktg * 32 + q * 8];
                    dacc[ct] = __builtin_amdgcn_mfma_f32_16x16x32_bf16(cl, wdf, dacc[ct], 0, 0, 0);
                }
                short8 hl = *(const short8*)&h_loc[l16][kt2 * 32 + q * 8];
                #pragma unroll
                for (int g = 0; g < 4; ++g)
                    #pragma unroll
                    for (int ct = 0; ct < 2; ++ct)
                        gacc[g][ct] = __builtin_amdgcn_mfma_f32_16x16x32_bf16(hl, wg[g][ct][ktg], gacc[g][ct], 0, 0, 0);
            }
        }

        // 4. REMOTE phase: wait gathers (+pv), then peer-half MFMAs
        asm volatile("s_waitcnt vmcnt(0)" ::: "memory");
        __builtin_amdgcn_sched_barrier(0);
        if (gt > 0) {
            #pragma unroll
            for (int kt2 = 0; kt2 < 4; ++kt2) {
                const int ktg = (half ^ 1) * 4 + kt2;
                #pragma unroll
                for (int ct = 0; ct < 2; ++ct) {
                    short8 wdf = *(const short8*)&wd_lds[colB0 + ct * 16 + l16][ktg * 32 + q * 8];
                    dacc[ct] = __builtin_amdgcn_mfma_f32_16x16x32_bf16(car[kt2], wdf, dacc[ct], 0, 0, 0);
                }
                #pragma unroll
                for (int g = 0; g < 4; ++g)
                    #pragma unroll
                    for (int ct = 0; ct < 2; ++ct)
                        gacc[g][ct] = __builtin_amdgcn_mfma_f32_16x16x32_bf16(har[kt2], wg[g][ct][ktg], gacc[g][ct], 0, 0, 0);
            }
        }

        // 5. all local LDS reads of h(t-1)/c(t-1) done -> safe to overwrite
        __syncthreads();

        // 6. elementwise + LDS update + peer-visible stores
        #pragma unroll
        for (int ct = 0; ct < 2; ++ct) {
            #pragma unroll
            for (int j = 0; j < 4; ++j) {
                int r = 4 * q + j;
                float tv = ts_lds[r][t];
                float cs1 = ftanh(dacc[ct][j]);
                float cadj = cf[ct][j] + cs1 * (tv - 1.0f);
                float fg = fsig(gacc[0][ct][j] + pv[0][ct][j]);
                float ig = fsig(gacc[1][ct][j] + pv[1][ct][j]);
                float og = fsig(gacc[2][ct][j] + pv[2][ct][j]);
                float cg = fsig(gacc[3][ct][j] + pv[3][ct][j]);
                float cn = fg * cadj + ig * cg;
                float hn = og * ftanh(cn);
                cf[ct][j] = cn;
                unsigned short hb = f2bf(hn), cb = f2bf(cn);
                int colB = colB0 + ct * 16 + l16;
                h_loc[r][colB] = hb;
                c_loc[r][colB] = cb;
                int mycol = half * 128 + colB;
                if (fast) {
                    gstore_short_plain(outp + ((long)(b0 + r) * S_ + gt) * H_ + mycol, (unsigned)hb);
                    gstore_short_plain(cx + ((long)((gt & 1) * 8 + grp)) * 4096 + r * 256 + mycol, (unsigned)cb);
                } else {
                    gstore_short_sc1(outp + ((long)(b0 + r) * S_ + gt) * H_ + mycol, (unsigned)hb);
                    gstore_short_sc1(cx + ((long)((gt & 1) * 8 + grp)) * 4096 + r * 256 + mycol, (unsigned)cb);
                }
            }
        }

        // 7. drain peer-visible data, then post own progress (AGENT RMW)
        asm volatile("s_waitcnt vmcnt(0)" ::: "memory");
        if (ln == 0)
            (void)__hip_atomic_fetch_add(own_cell, 1u, __ATOMIC_RELAXED, __HIP_MEMORY_SCOPE_AGENT);

        // 8. LDS writes visible before next step's local reads
        __syncthreads();
    }

    // persist fp32 c for next chunk (own cols)
    #pragma unroll
    for (int ct = 0; ct < 2; ++ct)
        #pragma unroll
        for (int j = 0; j < 4; ++j)
            cst[(long)(l * 4 + m) * 4096 + (4 * q + j) * 256 + half * 128 + colB0 + ct * 16 + l16] = cf[ct][j];
}

// ---------------------------------------------------------------- K4a: scores + softmax -> alpha
__global__ __launch_bounds__(512) void k4a_alpha(const unsigned short* __restrict__ out1,
                                                 const float* __restrict__ wa,
                                                 float* __restrict__ alpha) {
    __shared__ float sc[512];
    __shared__ float red[512];
    const int b = blockIdx.x, tid = threadIdx.x;
    const int w = tid >> 6, ln = tid & 63;
    f32x4 wv = *(const f32x4*)(wa + ln * 4);
    for (int i = 0; i < 64; ++i) {
        int s = w * 64 + i;
        const unsigned short* row = out1 + ((long)b * S_ + s) * H_ + ln * 4;
        float d = bf2f(row[0]) * wv[0] + bf2f(row[1]) * wv[1] +
                  bf2f(row[2]) * wv[2] + bf2f(row[3]) * wv[3];
        #pragma unroll
        for (int off = 32; off; off >>= 1) d += __shfl_xor(d, off);
        if (ln == 0) sc[s] = d;
    }
    __syncthreads();
    float v = sc[tid];
    red[tid] = v;
    for (int st = 256; st; st >>= 1) {
        __syncthreads();
        if (tid < st) red[tid] = fmaxf(red[tid], red[tid + st]);
    }
    __syncthreads();
    float M = red[0];
    __syncthreads();
    float e = __builtin_amdgcn_exp2f((v - M) * 1.44269504f);
    red[tid] = e;
    for (int st = 256; st; st >>= 1) {
        __syncthreads();
        if (tid < st) red[tid] += red[tid + st];
    }
    __syncthreads();
    alpha[b * S_ + tid] = e * __builtin_amdgcn_rcpf(red[0]);
}

// ---------------------------------------------------------------- K4b: Beta=tanh(out2@Wb^T); ctx = sum_s emb*Beta*alpha
__global__ __launch_bounds__(512, 2) void k4b_ctx(const unsigned short* __restrict__ out2,
                                                  const unsigned short* __restrict__ Wbb,
                                                  const unsigned short* __restrict__ embB,
                                                  const float* __restrict__ alpha,
                                                  float* __restrict__ ctx) {
    __shared__ float cbuf[32][256];
    const int b = blockIdx.x, tid = threadIdx.x;
    const int w = tid >> 6, ln = tid & 63, q = ln >> 4, l16 = ln & 15;

    float cp[16];
    #pragma unroll
    for (int nt = 0; nt < 16; ++nt) cp[nt] = 0.f;

    for (int i = 0; i < 4; ++i) {
        int mt = w * 4 + i;
        short8 af[8];
        #pragma unroll
        for (int kt = 0; kt < 8; ++kt)
            af[kt] = *(const short8*)(out2 + ((long)b * S_ + mt * 16 + l16) * H_ + kt * 32 + q * 8);
        float al[4];
        #pragma unroll
        for (int j = 0; j < 4; ++j) al[j] = alpha[b * S_ + mt * 16 + 4 * q + j];
        for (int nt = 0; nt < 16; ++nt) {
            f32x4 acc = (f32x4){0.f, 0.f, 0.f, 0.f};
            #pragma unroll
            for (int kt = 0; kt < 8; ++kt) {
                short8 bf = *(const short8*)(Wbb + (long)(nt * 16 + l16) * H_ + kt * 32 + q * 8);
                acc = __builtin_amdgcn_mfma_f32_16x16x32_bf16(af[kt], bf, acc, 0, 0, 0);
            }
            #pragma unroll
            for (int j = 0; j < 4; ++j) {
                int s = mt * 16 + 4 * q + j;
                float beta = ftanh(acc[j]);
                float ev = bf2f(embB[((long)b * S_ + s) * H_ + nt * 16 + l16]);
                cp[nt] += beta * al[j] * ev;
            }
        }
    }
    #pragma unroll
    for (int nt = 0; nt < 16; ++nt) cbuf[w * 4 + q][nt * 16 + l16] = cp[nt];
    __syncthreads();
    if (tid < 256) {
        float sum = 0.f;
        for (int i = 0; i < 32; ++i) sum += cbuf[i][tid];
        ctx[b * H_ + tid] = sum;
    }
}

// ---------------------------------------------------------------- K4c: out = ctx @ W_out^T
__global__ void k4c_out(const float* __restrict__ ctx, const float* __restrict__ Wout,
                        float* __restrict__ out) {
    int b = blockIdx.x, n = threadIdx.x;
    const f32x4* cr = (const f32x4*)(ctx + b * H_);
    const f32x4* wr = (const f32x4*)(Wout + n * H_);
    float acc = 0.f;
    #pragma unroll 8
    for (int i = 0; i < 64; ++i) {
        f32x4 c = cr[i], ww = wr[i];
        acc += c[0] * ww[0] + c[1] * ww[1] + c[2] * ww[2] + c[3] * ww[3];
    }
    out[b * NC_ + n] = acc;
}

// ---------------------------------------------------------------- launch
extern "C" void kernel_launch(void* const* d_in, const int* in_sizes, int n_in,
                              void* d_out, int out_size, void* d_ws, size_t ws_size,
                              hipStream_t stream) {
    (void)in_sizes; (void)n_in; (void)out_size;
    const float* inputs = (const float*)d_in[0];
    const float* tsp    = (const float*)d_in[1];
    const float* emb    = (const float*)d_in[2];
    const float* Wa1 = (const float*)d_in[3];  const float* ba1 = (const float*)d_in[4];
    const float* U1  = (const float*)d_in[5];  const float* bu1 = (const float*)d_in[6];
    const float* Wd1 = (const float*)d_in[7];  const float* bd1 = (const float*)d_in[8];
    const float* Wa2 = (const float*)d_in[9];  const float* ba2 = (const float*)d_in[10];
    const float* U2  = (const float*)d_in[11]; const float* bu2 = (const float*)d_in[12];
    const float* Wd2 = (const float*)d_in[13]; const float* bd2 = (const float*)d_in[14];
    const float* wa  = (const float*)d_in[15];
    const float* Wb  = (const float*)d_in[16];
    const float* Wout = (const float*)d_in[17];
    float* out = (float*)d_out;

    // Workspace map (round-14: layout as round-12; cnt zone reused).
    char* ws = (char*)d_ws;
    unsigned short* embT = (unsigned short*)(ws + 0);            //    720,896
    unsigned short* Wg   = (unsigned short*)(ws + 720896);       //  1,048,576 (Wd must follow)
    unsigned short* Wd   = (unsigned short*)(ws + 1769472);      //    262,144
    unsigned short* Ub   = (unsigned short*)(ws + 2031616);      //  1,048,576
    unsigned short* Wbb  = (unsigned short*)(ws + 3080192);      //    131,072
    float*          bgp  = (float*)(ws + 3211264);               //      8,192
    unsigned short* embB = (unsigned short*)(ws + 3219456);      // 16,777,216
    float*          P0   = (float*)(ws + 19996672);              // 33,554,432
    unsigned short* out1 = (unsigned short*)(ws + 53551104);     // 16,777,216
    unsigned short* out2 = (unsigned short*)(ws + 70328320);     // 16,777,216
    unsigned short* cx   = (unsigned short*)(ws + 87105536);     //    131,072
    float*          cst  = (float*)(ws + 87236608);              //    131,072
    float*          alp  = (float*)(ws + 87367680);              //    131,072
    float*          ctx  = (float*)(ws + 87498752);              //     65,536
    unsigned int*   cnt  = (unsigned int*)(ws + 87564288);       //    155,648
    float*          P1   = (float*)(ws + 87719936);              // 33,554,432 (fused path only)
    const size_t NEED_FUSED = 121274368;                         // 87,719,936 + 33,554,432
    const bool fuse = (ws_size >= NEED_FUSED);

    hipLaunchKernelGGL(k0_prep, dim3(256), dim3(256), 0, stream,
                       emb, Wa1, Wa2, Wd1, Wd2, U1, U2, ba1, bu1, ba2, bu2, Wb,
                       embT, Wg, Wd, Ub, Wbb, bgp, cnt);
    hipLaunchKernelGGL(k1_embed, dim3(1024), dim3(512), 0, stream, inputs, embT, embB);
    // prologue: P(chunk 0)
    hipLaunchKernelGGL(k2_pre, dim3(128), dim3(512), 0, stream, embB, Ub, bgp, P0, 0);

    float* Pb[2] = { P0, fuse ? P1 : P0 };
    for (int c = 0; c < 8; ++c) {
        if (fuse) {
            int ng = (c < 7) ? 256 : 0;
            hipLaunchKernelGGL(k3_fused, dim3(16 + ng), dim3(256), 0, stream,
                               tsp, Wg, bd1, bd2, Pb[c & 1], out1, out2, cst, cx, cnt, c * CH_,
                               embB, Ub, bgp, Pb[(c + 1) & 1], (c + 1) * CH_);
        } else {
            if (c > 0)
                hipLaunchKernelGGL(k2_pre, dim3(128), dim3(512), 0, stream, embB, Ub, bgp, P0, c * CH_);
            hipLaunchKernelGGL(k3_fused, dim3(16), dim3(256), 0, stream,
                               tsp, Wg, bd1, bd2, P0, out1, out2, cst, cx, cnt, c * CH_,
                               embB, Ub, bgp, P0, S_ /* unused: no GEMM blocks */);
        }
    }
    hipLaunchKernelGGL(k4a_alpha, dim3(64), dim3(512), 0, stream, out1, wa, alp);
    hipLaunchKernelGGL(k4b_ctx, dim3(64), dim3(512), 0, stream, out2, Wbb, embB, alp, ctx);
    hipLaunchKernelGGL(k4c_out, dim3(64), dim3(128), 0, stream, ctx, Wout, out);
}

// Round 10
// 4597.523 us; speedup vs baseline: 1.4823x; 1.4823x over previous
//
#include <hip/hip_runtime.h>

typedef __attribute__((ext_vector_type(8))) short short8;
typedef __attribute__((ext_vector_type(4))) float f32x4;

#define B_   64
#define S_   512
#define V_   1400
#define VP_  1408
#define H_   256
#define G4_  1024
#define NC_  128
#define CH_  64    // time-chunk length (8 chunks of 64 steps)

__device__ __forceinline__ unsigned short f2bf(float f) {
    unsigned u = __builtin_bit_cast(unsigned, f);
    u += 0x7FFFu + ((u >> 16) & 1u);
    return (unsigned short)(u >> 16);
}
__device__ __forceinline__ float bf2f(unsigned short h) {
    unsigned u = ((unsigned)h) << 16;
    return __builtin_bit_cast(float, u);
}
__device__ __forceinline__ float fsig(float x) {
    x = fminf(fmaxf(x, -40.f), 40.f);
    float e = __builtin_amdgcn_exp2f(x * -1.44269504f);
    return __builtin_amdgcn_rcpf(1.0f + e);
}
__device__ __forceinline__ float ftanh(float x) {
    x = fminf(fmaxf(x, -40.f), 40.f);
    float e = __builtin_amdgcn_exp2f(x * 2.88539008f);
    return 1.0f - 2.0f * __builtin_amdgcn_rcpf(e + 1.0f);
}

// ---- IC-coherent data primitives (proven r2/r7) ----
__device__ __forceinline__ short8 gload16_sc1(const unsigned short* p) {
    short8 r;
    asm volatile("global_load_dwordx4 %0, %1, off sc1"
                 : "=&v"(r) : "v"((unsigned long long)p));
    return r;
}
__device__ __forceinline__ void gstore_short_sc1(unsigned short* p, unsigned v) {
    asm volatile("global_store_short %0, %1, off sc1"
                 :: "v"((unsigned long long)p), "v"(v));
}
// plain dword load via asm — ordered among the volatile-asm vmem stream so the
// staged vmcnt(24)/(16)/(0) counts are exact. (P is cross-dispatch data; plain
// loads were proven for it in r7.)
__device__ __forceinline__ float gloadf_plain(const float* p) {
    float r;
    asm volatile("global_load_dword %0, %1, off"
                 : "=&v"(r) : "v"((unsigned long long)p));
    return r;
}

// cnt zone (ints): chain cells at (chunk*8+grp)*64, 256B-spaced  [0,4096)
#define CNT_ZONE_ 4096

// ---------------------------------------------------------------- K0: prep
__global__ void k0_prep(const float* __restrict__ emb,
                        const float* __restrict__ Wa1, const float* __restrict__ Wa2,
                        const float* __restrict__ Wd1, const float* __restrict__ Wd2,
                        const float* __restrict__ U1,  const float* __restrict__ U2,
                        const float* __restrict__ ba1, const float* __restrict__ bu1,
                        const float* __restrict__ ba2, const float* __restrict__ bu2,
                        const float* __restrict__ Wb,
                        unsigned short* __restrict__ embT, unsigned short* __restrict__ Wg,
                        unsigned short* __restrict__ Wd,   unsigned short* __restrict__ Ub,
                        unsigned short* __restrict__ Wbb,  float* __restrict__ bg,
                        unsigned int* __restrict__ cnt) {
    int tid = blockIdx.x * blockDim.x + threadIdx.x;
    int np = gridDim.x * blockDim.x;
    for (int i = tid; i < 256 * VP_; i += np) {
        int n = i / VP_, k = i - n * VP_;
        embT[i] = (k < V_) ? f2bf(emb[k * H_ + n]) : (unsigned short)0;
    }
    for (int i = tid; i < G4_ * H_; i += np) {
        Wg[i] = f2bf(Wa1[i]); Wg[G4_ * H_ + i] = f2bf(Wa2[i]);
        Ub[i] = f2bf(U1[i]);  Ub[G4_ * H_ + i] = f2bf(U2[i]);
    }
    for (int i = tid; i < H_ * H_; i += np) {
        Wd[i] = f2bf(Wd1[i]); Wd[H_ * H_ + i] = f2bf(Wd2[i]); Wbb[i] = f2bf(Wb[i]);
    }
    for (int i = tid; i < G4_; i += np) {
        bg[i] = ba1[i] + bu1[i]; bg[G4_ + i] = ba2[i] + bu2[i];
    }
    for (int i = tid; i < CNT_ZONE_; i += np) cnt[i] = 0;   // chain cells, re-zeroed every run
}

// ---------------------------------------------------------------- K1: embedded = inputs @ emb
__global__ __launch_bounds__(512, 2) void k1_embed(const float* __restrict__ inputs,
                                                   const unsigned short* __restrict__ embT,
                                                   unsigned short* __restrict__ embB) {
    const int tid = threadIdx.x;
    const int w = tid >> 6, ln = tid & 63, q = ln >> 4, l16 = ln & 15;
    const int mt = w >> 2, ng = (w & 3) * 4;
    const int Rbase = blockIdx.x * 32 + mt * 16;
    const float* arow = inputs + (long)(Rbase + l16) * V_;

    f32x4 acc[4];
    #pragma unroll
    for (int i = 0; i < 4; ++i) acc[i] = (f32x4){0.f, 0.f, 0.f, 0.f};

    for (int kt = 0; kt < 44; ++kt) {
        int k0 = kt * 32 + q * 8;
        short8 af;
        if (kt == 43 && q == 3) {
            #pragma unroll
            for (int j = 0; j < 8; ++j) af[j] = 0;
        } else {
            f32x4 x0 = *(const f32x4*)(arow + k0);
            f32x4 x1 = *(const f32x4*)(arow + k0 + 4);
            #pragma unroll
            for (int j = 0; j < 4; ++j) { af[j] = (short)f2bf(x0[j]); af[4 + j] = (short)f2bf(x1[j]); }
        }
        #pragma unroll
        for (int i = 0; i < 4; ++i) {
            short8 bf = *(const short8*)(embT + (long)((ng + i) * 16 + l16) * VP_ + k0);
            acc[i] = __builtin_amdgcn_mfma_f32_16x16x32_bf16(af, bf, acc[i], 0, 0, 0);
        }
    }
    #pragma unroll
    for (int i = 0; i < 4; ++i) {
        int col = (ng + i) * 16 + l16;
        #pragma unroll
        for (int j = 0; j < 4; ++j) {
            int R = Rbase + 4 * q + j;
            embB[(long)R * H_ + col] = f2bf(acc[i][j]);
        }
    }
}

// ---------------------------------------------------------------- K2: P chunk = embedded @ [U1;U2]^T + bg
// (chunk-0 prologue and no-fuse fallback)
__global__ __launch_bounds__(512, 2) void k2_pre(const unsigned short* __restrict__ embB,
                                                 const unsigned short* __restrict__ Ub,
                                                 const float* __restrict__ bg,
                                                 float* __restrict__ P, int t0) {
    const int tid = threadIdx.x;
    const int w = tid >> 6, ln = tid & 63, q = ln >> 4, l16 = ln & 15;
    const int rbase = blockIdx.x * 32;  // local row' in chunk, 0..4095

    short8 af[2][8];
    #pragma unroll
    for (int mt = 0; mt < 2; ++mt)
        #pragma unroll
        for (int kt = 0; kt < 8; ++kt) {
            int rp = rbase + mt * 16 + l16;
            int rg = t0 * 64 + rp;
            int b = rg & 63, s = rg >> 6;
            af[mt][kt] = *(const short8*)(embB + ((long)b * S_ + s) * H_ + kt * 32 + q * 8);
        }

    for (int i = 0; i < 16; ++i) {
        int nt2 = w * 16 + i;          // global gate-col tile 0..127
        int l = nt2 >> 6;
        int gcol = (nt2 & 63) * 16 + l16;   // col within lstm, 0..1023
        float bias = bg[nt2 * 16 + l16];
        short8 bf[8];
        #pragma unroll
        for (int kt = 0; kt < 8; ++kt)
            bf[kt] = *(const short8*)(Ub + (long)(nt2 * 16 + l16) * H_ + kt * 32 + q * 8);
        #pragma unroll
        for (int mt = 0; mt < 2; ++mt) {
            f32x4 acc = (f32x4){bias, bias, bias, bias};
            #pragma unroll
            for (int kt = 0; kt < 8; ++kt)
                acc = __builtin_amdgcn_mfma_f32_16x16x32_bf16(af[mt][kt], bf[kt], acc, 0, 0, 0);
            int rp0 = rbase + mt * 16;
            float* dst = P + ((long)l * (CH_ * 64) + rp0 + 4 * q) * G4_ + gcol;
            #pragma unroll
            for (int j = 0; j < 4; ++j) dst[(long)j * G4_] = acc[j];
        }
    }
}

// ---------------------------------------------------------------- K3: fused LSTM (2 chains/block) + next-chunk P GEMM
// Round-15: rendezvous-latency HIDING via chain interleave.
//   Nine rounds showed the post->detect rendezvous is a fixed ~2.5-4us
//   latency through the coherent point, insensitive to primitive/scope/peer
//   count (r2 257 / r6 270 / r7 273 / r8 300 / r9-pair 775). The 8 recurrence
//   chains (2 lstm x 4 batch-tiles) are INDEPENDENT -> each block hosts TWO
//   chains with the same l (weights shared, zero extra cost): per iteration
//   {pollA, workA, postA, pollB, workB, postB}. Each chain's rendezvous
//   latency hides under the other chain's compute -> detection collapses to
//   ~1 round trip. Per-chain protocol is byte-identical to the proven set:
//   sc1 stores/gathers (r2), per-wave AGENT RMW post after drain + lane0 RMW
//   poll (r6/r7), bounded; no handshake (scope proven irrelevant). pv loads
//   via ordered volatile asm AFTER gathers: vmcnt(24)=ca, (16)=ha, (0)=pv.
__global__ __launch_bounds__(256, 1) void k3_fused(const float* __restrict__ ts,
                                                   const unsigned short* __restrict__ W, // Wg || Wd
                                                   const float* __restrict__ bd1,
                                                   const float* __restrict__ bd2,
                                                   const float* __restrict__ Pcur,
                                                   unsigned short* __restrict__ out1,
                                                   unsigned short* __restrict__ out2,
                                                   float* __restrict__ cst,
                                                   unsigned short* __restrict__ cx,
                                                   unsigned int* __restrict__ cnt,
                                                   int t0,
                                                   const unsigned short* __restrict__ embB,
                                                   const unsigned short* __restrict__ Ub,
                                                   const float* __restrict__ bg,
                                                   float* __restrict__ Pnext,
                                                   int next_t0) {
    const int tid = threadIdx.x;
    const int w = tid >> 6, ln = tid & 63, q = ln >> 4, l16 = ln & 15;
    const int bid = blockIdx.x;

    if (bid >= 16) {
        // ================= GEMM role: P(next chunk) = embB @ Ub^T + bg =======
        const int g2 = bid - 16;
        const int rbase = (g2 >> 1) * 32;
        const int hb = g2 & 1;

        short8 af[2][8];
        #pragma unroll
        for (int mt = 0; mt < 2; ++mt)
            #pragma unroll
            for (int kt = 0; kt < 8; ++kt) {
                int rp = rbase + mt * 16 + l16;
                int rg = next_t0 * 64 + rp;
                int b = rg & 63, s = rg >> 6;
                af[mt][kt] = *(const short8*)(embB + ((long)b * S_ + s) * H_ + kt * 32 + q * 8);
            }

        for (int i = 0; i < 16; ++i) {
            int nt2 = hb * 64 + w * 16 + i;
            int l = nt2 >> 6;
            int gcol = (nt2 & 63) * 16 + l16;
            float bias = bg[nt2 * 16 + l16];
            short8 bf[8];
            #pragma unroll
            for (int kt = 0; kt < 8; ++kt)
                bf[kt] = *(const short8*)(Ub + (long)(nt2 * 16 + l16) * H_ + kt * 32 + q * 8);
            #pragma unroll
            for (int mt = 0; mt < 2; ++mt) {
                f32x4 acc = (f32x4){bias, bias, bias, bias};
                #pragma unroll
                for (int kt = 0; kt < 8; ++kt)
                    acc = __builtin_amdgcn_mfma_f32_16x16x32_bf16(af[mt][kt], bf[kt], acc, 0, 0, 0);
                int rp0 = rbase + mt * 16;
                float* dst = Pnext + ((long)l * (CH_ * 64) + rp0 + 4 * q) * G4_ + gcol;
                #pragma unroll
                for (int j = 0; j < 4; ++j) dst[(long)j * G4_] = acc[j];
            }
        }
        return;
    }

    // ==================== LSTM role (blocks 0..15, 2 chains each) ============
    __shared__ float ts_lds[2][16][CH_];    // 8 KB
    const int chunk = t0 >> 6;

    // block decode: l = lstm, mp = batch-pair, cg = col-group
    const int l = bid >> 3, mp = (bid >> 2) & 1, cg = bid & 3;
    const int mA = mp, mB = mp + 2;
    const int grpA = l * 4 + mA, grpB = l * 4 + mB;
    const int b0A = mA * 16, b0B = mB * 16;
    const int hc0 = cg * 64 + w * 16;
    const int mycol = hc0 + l16;
    unsigned int* cellA = cnt + (chunk * 8 + grpA) * 64;
    unsigned int* cellB = cnt + (chunk * 8 + grpB) * 64;
    unsigned short* outp = l ? out2 : out1;
    const float bdv = (l ? bd2 : bd1)[mycol];

    for (int i = tid; i < 2 * 16 * CH_; i += 256) {
        int ch = i >> 10, r = (i >> 6) & 15, cc = i & (CH_ - 1);
        int b0 = (ch ? b0B : b0A);
        ts_lds[ch][r][cc] = ts[(b0 + r) * S_ + t0 + cc];
    }

    // -------- register/AGPR-resident weights (shared by both chains) --------
    short8 wg[4][8];
    short8 wd[8];
    #pragma unroll
    for (int g = 0; g < 4; ++g)
        #pragma unroll
        for (int kt = 0; kt < 8; ++kt)
            wg[g][kt] = *(const short8*)(W + ((long)(l * G4_ + g * H_ + mycol)) * H_ + kt * 32 + q * 8);
    #pragma unroll
    for (int kt = 0; kt < 8; ++kt)
        wd[kt] = *(const short8*)(W + (long)2 * G4_ * H_ + ((long)(l * H_ + mycol)) * H_ + kt * 32 + q * 8);

    float cfA[4], cfB[4];
    if (t0 == 0) {
        #pragma unroll
        for (int j = 0; j < 4; ++j) { cfA[j] = 0.f; cfB[j] = 0.f; }
    } else {
        #pragma unroll
        for (int j = 0; j < 4; ++j) {
            cfA[j] = cst[(long)grpA * 4096 + (4 * q + j) * 256 + mycol];
            cfB[j] = cst[(long)grpB * 4096 + (4 * q + j) * 256 + mycol];
        }
    }
    __syncthreads();   // ts_lds ready

    const float* PbA = Pcur + ((long)l * (CH_ * 64) + b0A) * G4_;
    const float* PbB = Pcur + ((long)l * (CH_ * 64) + b0B) * G4_;
    unsigned opaque_zero;
    asm volatile("v_mov_b32 %0, 0" : "=v"(opaque_zero));

    // one chain-step (fully inlined twice per iteration; all indices static)
    auto chain_step = [&](int t, int gt, int b0, int grp, unsigned int* cell,
                          float (&cf)[4], const float (*tsrow)[CH_], const float* PbC) {
        if (t) {
            const unsigned tgt = 16u * (unsigned)t;
            unsigned it = 0;
            for (;;) {
                unsigned v = 0;
                if (ln == 0)
                    v = __hip_atomic_fetch_add(cell, opaque_zero,
                                               __ATOMIC_RELAXED, __HIP_MEMORY_SCOPE_AGENT);
                v = __shfl(v, 0);
                if (v >= tgt || ++it >= (1u << 14)) break;
            }
        }
        __builtin_amdgcn_sched_barrier(0);

        short8 ha[8], ca[8];
        if (gt == 0) {
            #pragma unroll
            for (int kt = 0; kt < 8; ++kt) {
                #pragma unroll
                for (int jj = 0; jj < 8; ++jj) { ha[kt][jj] = 0; ca[kt][jj] = 0; }
            }
        } else {
            const unsigned short* crow = cx + ((long)(((gt - 1) & 1) * 8 + grp)) * 4096 + l16 * 256 + q * 8;
            const unsigned short* hrow = outp + ((long)(b0 + l16) * S_ + (gt - 1)) * H_ + q * 8;
            #pragma unroll
            for (int kt = 0; kt < 8; ++kt) ca[kt] = gload16_sc1(crow + kt * 32);
            #pragma unroll
            for (int kt = 0; kt < 8; ++kt) ha[kt] = gload16_sc1(hrow + kt * 32);
        }
        // pv issued AFTER the gathers (ordered volatile asm) -> exact vmcnt staging
        float pv[4][4];
        #pragma unroll
        for (int g = 0; g < 4; ++g)
            #pragma unroll
            for (int j = 0; j < 4; ++j)
                pv[g][j] = gloadf_plain(PbC + ((long)t * 64 + 4 * q + j) * G4_ + g * H_ + mycol);

        asm volatile("s_waitcnt vmcnt(24)" ::: "memory");   // ca complete (no-op at gt==0)
        __builtin_amdgcn_sched_barrier(0);
        f32x4 dacc = (f32x4){bdv, bdv, bdv, bdv};
        #pragma unroll
        for (int kt = 0; kt < 8; ++kt)
            dacc = __builtin_amdgcn_mfma_f32_16x16x32_bf16(ca[kt], wd[kt], dacc, 0, 0, 0);

        asm volatile("s_waitcnt vmcnt(16)" ::: "memory");   // ha complete
        __builtin_amdgcn_sched_barrier(0);
        f32x4 gacc[4];
        #pragma unroll
        for (int g = 0; g < 4; ++g) {
            gacc[g] = (f32x4){0.f, 0.f, 0.f, 0.f};
            #pragma unroll
            for (int kt = 0; kt < 8; ++kt)
                gacc[g] = __builtin_amdgcn_mfma_f32_16x16x32_bf16(ha[kt], wg[g][kt], gacc[g], 0, 0, 0);
        }

        asm volatile("s_waitcnt vmcnt(0)" ::: "memory");    // pv complete
        __builtin_amdgcn_sched_barrier(0);
        #pragma unroll
        for (int j = 0; j < 4; ++j) {
            int r = 4 * q + j;
            float tv = tsrow[r][t];
            float cs1 = ftanh(dacc[j]);
            float cadj = cf[j] + cs1 * (tv - 1.0f);
            float fg = fsig(gacc[0][j] + pv[0][j]);
            float ig = fsig(gacc[1][j] + pv[1][j]);
            float og = fsig(gacc[2][j] + pv[2][j]);
            float cg2 = fsig(gacc[3][j] + pv[3][j]);
            float cn = fg * cadj + ig * cg2;
            float hn = og * ftanh(cn);
            cf[j] = cn;
            gstore_short_sc1(outp + ((long)(b0 + r) * S_ + gt) * H_ + mycol, (unsigned)f2bf(hn));
            gstore_short_sc1(cx + ((long)((gt & 1) * 8 + grp)) * 4096 + r * 256 + mycol, (unsigned)f2bf(cn));
        }
        asm volatile("s_waitcnt vmcnt(0)" ::: "memory");    // peer-visible data drained
        if (ln == 0)
            (void)__hip_atomic_fetch_add(cell, 1u, __ATOMIC_RELAXED, __HIP_MEMORY_SCOPE_AGENT);
    };

    #pragma unroll 1
    for (int t = 0; t < CH_; ++t) {
        const int gt = t0 + t;
        chain_step(t, gt, b0A, grpA, cellA, cfA, ts_lds[0], PbA);
        chain_step(t, gt, b0B, grpB, cellB, cfB, ts_lds[1], PbB);
    }

    // persist fp32 c for next chunk (both chains)
    #pragma unroll
    for (int j = 0; j < 4; ++j) {
        cst[(long)grpA * 4096 + (4 * q + j) * 256 + mycol] = cfA[j];
        cst[(long)grpB * 4096 + (4 * q + j) * 256 + mycol] = cfB[j];
    }
}

// ---------------------------------------------------------------- K4a: scores + softmax -> alpha
__global__ __launch_bounds__(512) void k4a_alpha(const unsigned short* __restrict__ out1,
                                                 const float* __restrict__ wa,
                                                 float* __restrict__ alpha) {
    __shared__ float sc[512];
    __shared__ float red[512];
    const int b = blockIdx.x, tid = threadIdx.x;
    const int w = tid >> 6, ln = tid & 63;
    f32x4 wv = *(const f32x4*)(wa + ln * 4);
    for (int i = 0; i < 64; ++i) {
        int s = w * 64 + i;
        const unsigned short* row = out1 + ((long)b * S_ + s) * H_ + ln * 4;
        float d = bf2f(row[0]) * wv[0] + bf2f(row[1]) * wv[1] +
                  bf2f(row[2]) * wv[2] + bf2f(row[3]) * wv[3];
        #pragma unroll
        for (int off = 32; off; off >>= 1) d += __shfl_xor(d, off);
        if (ln == 0) sc[s] = d;
    }
    __syncthreads();
    float v = sc[tid];
    red[tid] = v;
    for (int st = 256; st; st >>= 1) {
        __syncthreads();
        if (tid < st) red[tid] = fmaxf(red[tid], red[tid + st]);
    }
    __syncthreads();
    float M = red[0];
    __syncthreads();
    float e = __builtin_amdgcn_exp2f((v - M) * 1.44269504f);
    red[tid] = e;
    for (int st = 256; st; st >>= 1) {
        __syncthreads();
        if (tid < st) red[tid] += red[tid + st];
    }
    __syncthreads();
    alpha[b * S_ + tid] = e * __builtin_amdgcn_rcpf(red[0]);
}

// ---------------------------------------------------------------- K4b: Beta=tanh(out2@Wb^T); ctx = sum_s emb*Beta*alpha
__global__ __launch_bounds__(512, 2) void k4b_ctx(const unsigned short* __restrict__ out2,
                                                  const unsigned short* __restrict__ Wbb,
                                                  const unsigned short* __restrict__ embB,
                                                  const float* __restrict__ alpha,
                                                  float* __restrict__ ctx) {
    __shared__ float cbuf[32][256];
    const int b = blockIdx.x, tid = threadIdx.x;
    const int w = tid >> 6, ln = tid & 63, q = ln >> 4, l16 = ln & 15;

    float cp[16];
    #pragma unroll
    for (int nt = 0; nt < 16; ++nt) cp[nt] = 0.f;

    for (int i = 0; i < 4; ++i) {
        int mt = w * 4 + i;
        short8 af[8];
        #pragma unroll
        for (int kt = 0; kt < 8; ++kt)
            af[kt] = *(const short8*)(out2 + ((long)b * S_ + mt * 16 + l16) * H_ + kt * 32 + q * 8);
        float al[4];
        #pragma unroll
        for (int j = 0; j < 4; ++j) al[j] = alpha[b * S_ + mt * 16 + 4 * q + j];
        for (int nt = 0; nt < 16; ++nt) {
            f32x4 acc = (f32x4){0.f, 0.f, 0.f, 0.f};
            #pragma unroll
            for (int kt = 0; kt < 8; ++kt) {
                short8 bf = *(const short8*)(Wbb + (long)(nt * 16 + l16) * H_ + kt * 32 + q * 8);
                acc = __builtin_amdgcn_mfma_f32_16x16x32_bf16(af[kt], bf, acc, 0, 0, 0);
            }
            #pragma unroll
            for (int j = 0; j < 4; ++j) {
                int s = mt * 16 + 4 * q + j;
                float beta = ftanh(acc[j]);
                float ev = bf2f(embB[((long)b * S_ + s) * H_ + nt * 16 + l16]);
                cp[nt] += beta * al[j] * ev;
            }
        }
    }
    #pragma unroll
    for (int nt = 0; nt < 16; ++nt) cbuf[w * 4 + q][nt * 16 + l16] = cp[nt];
    __syncthreads();
    if (tid < 256) {
        float sum = 0.f;
        for (int i = 0; i < 32; ++i) sum += cbuf[i][tid];
        ctx[b * H_ + tid] = sum;
    }
}

// ---------------------------------------------------------------- K4c: out = ctx @ W_out^T
__global__ void k4c_out(const float* __restrict__ ctx, const float* __restrict__ Wout,
                        float* __restrict__ out) {
    int b = blockIdx.x, n = threadIdx.x;
    const f32x4* cr = (const f32x4*)(ctx + b * H_);
    const f32x4* wr = (const f32x4*)(Wout + n * H_);
    float acc = 0.f;
    #pragma unroll 8
    for (int i = 0; i < 64; ++i) {
        f32x4 c = cr[i], ww = wr[i];
        acc += c[0] * ww[0] + c[1] * ww[1] + c[2] * ww[2] + c[3] * ww[3];
    }
    out[b * NC_ + n] = acc;
}

// ---------------------------------------------------------------- launch
extern "C" void kernel_launch(void* const* d_in, const int* in_sizes, int n_in,
                              void* d_out, int out_size, void* d_ws, size_t ws_size,
                              hipStream_t stream) {
    (void)in_sizes; (void)n_in; (void)out_size;
    const float* inputs = (const float*)d_in[0];
    const float* tsp    = (const float*)d_in[1];
    const float* emb    = (const float*)d_in[2];
    const float* Wa1 = (const float*)d_in[3];  const float* ba1 = (const float*)d_in[4];
    const float* U1  = (const float*)d_in[5];  const float* bu1 = (const float*)d_in[6];
    const float* Wd1 = (const float*)d_in[7];  const float* bd1 = (const float*)d_in[8];
    const float* Wa2 = (const float*)d_in[9];  const float* ba2 = (const float*)d_in[10];
    const float* U2  = (const float*)d_in[11]; const float* bu2 = (const float*)d_in[12];
    const float* Wd2 = (const float*)d_in[13]; const float* bd2 = (const float*)d_in[14];
    const float* wa  = (const float*)d_in[15];
    const float* Wb  = (const float*)d_in[16];
    const float* Wout = (const float*)d_in[17];
    float* out = (float*)d_out;

    // Workspace map (round-15: layout as round-12/13).
    char* ws = (char*)d_ws;
    unsigned short* embT = (unsigned short*)(ws + 0);            //    720,896
    unsigned short* Wg   = (unsigned short*)(ws + 720896);       //  1,048,576 (Wd must follow)
    unsigned short* Wd   = (unsigned short*)(ws + 1769472);      //    262,144
    unsigned short* Ub   = (unsigned short*)(ws + 2031616);      //  1,048,576
    unsigned short* Wbb  = (unsigned short*)(ws + 3080192);      //    131,072
    float*          bgp  = (float*)(ws + 3211264);               //      8,192
    unsigned short* embB = (unsigned short*)(ws + 3219456);      // 16,777,216
    float*          P0   = (float*)(ws + 19996672);              // 33,554,432
    unsigned short* out1 = (unsigned short*)(ws + 53551104);     // 16,777,216
    unsigned short* out2 = (unsigned short*)(ws + 70328320);     // 16,777,216
    unsigned short* cx   = (unsigned short*)(ws + 87105536);     //    131,072
    float*          cst  = (float*)(ws + 87236608);              //    131,072
    float*          alp  = (float*)(ws + 87367680);              //    131,072
    float*          ctx  = (float*)(ws + 87498752);              //     65,536
    unsigned int*   cnt  = (unsigned int*)(ws + 87564288);       //    155,648
    float*          P1   = (float*)(ws + 87719936);              // 33,554,432 (fused path only)
    const size_t NEED_FUSED = 121274368;                         // 87,719,936 + 33,554,432
    const bool fuse = (ws_size >= NEED_FUSED);

    hipLaunchKernelGGL(k0_prep, dim3(256), dim3(256), 0, stream,
                       emb, Wa1, Wa2, Wd1, Wd2, U1, U2, ba1, bu1, ba2, bu2, Wb,
                       embT, Wg, Wd, Ub, Wbb, bgp, cnt);
    hipLaunchKernelGGL(k1_embed, dim3(1024), dim3(512), 0, stream, inputs, embT, embB);
    // prologue: P(chunk 0)
    hipLaunchKernelGGL(k2_pre, dim3(128), dim3(512), 0, stream, embB, Ub, bgp, P0, 0);

    float* Pb[2] = { P0, fuse ? P1 : P0 };
    for (int c = 0; c < 8; ++c) {
        if (fuse) {
            int ng = (c < 7) ? 256 : 0;
            hipLaunchKernelGGL(k3_fused, dim3(16 + ng), dim3(256), 0, stream,
                               tsp, Wg, bd1, bd2, Pb[c & 1], out1, out2, cst, cx, cnt, c * CH_,
                               embB, Ub, bgp, Pb[(c + 1) & 1], (c + 1) * CH_);
        } else {
            if (c > 0)
                hipLaunchKernelGGL(k2_pre, dim3(128), dim3(512), 0, stream, embB, Ub, bgp, P0, c * CH_);
            hipLaunchKernelGGL(k3_fused, dim3(16), dim3(256), 0, stream,
                               tsp, Wg, bd1, bd2, P0, out1, out2, cst, cx, cnt, c * CH_,
                               embB, Ub, bgp, P0, S_ /* unused: no GEMM blocks */);
        }
    }
    hipLaunchKernelGGL(k4a_alpha, dim3(64), dim3(512), 0, stream, out1, wa, alp);
    hipLaunchKernelGGL(k4b_ctx, dim3(64), dim3(512), 0, stream, out2, Wbb, embB, alp, ctx);
    hipLaunchKernelGGL(k4c_out, dim3(64), dim3(128), 0, stream, ctx, Wout, out);
}

// Round 11
// 2841.130 us; speedup vs baseline: 2.3987x; 1.6182x over previous
//
#include <hip/hip_runtime.h>

typedef __attribute__((ext_vector_type(8))) short short8;
typedef __attribute__((ext_vector_type(4))) float f32x4;

#define B_   64
#define S_   512
#define V_   1400
#define VP_  1408
#define H_   256
#define G4_  1024
#define NC_  128
#define CH_  64    // time-chunk length (8 chunks of 64 steps)

__device__ __forceinline__ unsigned short f2bf(float f) {
    unsigned u = __builtin_bit_cast(unsigned, f);
    u += 0x7FFFu + ((u >> 16) & 1u);
    return (unsigned short)(u >> 16);
}
__device__ __forceinline__ float bf2f(unsigned short h) {
    unsigned u = ((unsigned)h) << 16;
    return __builtin_bit_cast(float, u);
}
__device__ __forceinline__ float fsig(float x) {
    x = fminf(fmaxf(x, -40.f), 40.f);
    float e = __builtin_amdgcn_exp2f(x * -1.44269504f);
    return __builtin_amdgcn_rcpf(1.0f + e);
}
__device__ __forceinline__ float ftanh(float x) {
    x = fminf(fmaxf(x, -40.f), 40.f);
    float e = __builtin_amdgcn_exp2f(x * 2.88539008f);
    return 1.0f - 2.0f * __builtin_amdgcn_rcpf(e + 1.0f);
}

// ---- IC-coherent data primitives (proven r2/r7) ----
__device__ __forceinline__ short8 gload16_sc1(const unsigned short* p) {
    short8 r;
    asm volatile("global_load_dwordx4 %0, %1, off sc1"
                 : "=&v"(r) : "v"((unsigned long long)p));
    return r;
}
__device__ __forceinline__ void gstore_short_sc1(unsigned short* p, unsigned v) {
    asm volatile("global_store_short %0, %1, off sc1"
                 :: "v"((unsigned long long)p), "v"(v));
}
// plain dword load via asm — ordered among the volatile-asm vmem stream so the
// staged vmcnt(24)/(16)/(0) counts are exact (r10-validated bit-correct).
__device__ __forceinline__ float gloadf_plain(const float* p) {
    float r;
    asm volatile("global_load_dword %0, %1, off"
                 : "=&v"(r) : "v"((unsigned long long)p));
    return r;
}

// cnt zone (ints): chain cells at (chunk*8+grp)*64, 256B-spaced  [0,4096)
#define CNT_ZONE_ 4096

// ---------------------------------------------------------------- K0: prep
__global__ void k0_prep(const float* __restrict__ emb,
                        const float* __restrict__ Wa1, const float* __restrict__ Wa2,
                        const float* __restrict__ Wd1, const float* __restrict__ Wd2,
                        const float* __restrict__ U1,  const float* __restrict__ U2,
                        const float* __restrict__ ba1, const float* __restrict__ bu1,
                        const float* __restrict__ ba2, const float* __restrict__ bu2,
                        const float* __restrict__ Wb,
                        unsigned short* __restrict__ embT, unsigned short* __restrict__ Wg,
                        unsigned short* __restrict__ Wd,   unsigned short* __restrict__ Ub,
                        unsigned short* __restrict__ Wbb,  float* __restrict__ bg,
                        unsigned int* __restrict__ cnt) {
    int tid = blockIdx.x * blockDim.x + threadIdx.x;
    int np = gridDim.x * blockDim.x;
    for (int i = tid; i < 256 * VP_; i += np) {
        int n = i / VP_, k = i - n * VP_;
        embT[i] = (k < V_) ? f2bf(emb[k * H_ + n]) : (unsigned short)0;
    }
    for (int i = tid; i < G4_ * H_; i += np) {
        Wg[i] = f2bf(Wa1[i]); Wg[G4_ * H_ + i] = f2bf(Wa2[i]);
        Ub[i] = f2bf(U1[i]);  Ub[G4_ * H_ + i] = f2bf(U2[i]);
    }
    for (int i = tid; i < H_ * H_; i += np) {
        Wd[i] = f2bf(Wd1[i]); Wd[H_ * H_ + i] = f2bf(Wd2[i]); Wbb[i] = f2bf(Wb[i]);
    }
    for (int i = tid; i < G4_; i += np) {
        bg[i] = ba1[i] + bu1[i]; bg[G4_ + i] = ba2[i] + bu2[i];
    }
    for (int i = tid; i < CNT_ZONE_; i += np) cnt[i] = 0;   // chain cells, re-zeroed every run
}

// ---------------------------------------------------------------- K1: embedded = inputs @ emb
__global__ __launch_bounds__(512, 2) void k1_embed(const float* __restrict__ inputs,
                                                   const unsigned short* __restrict__ embT,
                                                   unsigned short* __restrict__ embB) {
    const int tid = threadIdx.x;
    const int w = tid >> 6, ln = tid & 63, q = ln >> 4, l16 = ln & 15;
    const int mt = w >> 2, ng = (w & 3) * 4;
    const int Rbase = blockIdx.x * 32 + mt * 16;
    const float* arow = inputs + (long)(Rbase + l16) * V_;

    f32x4 acc[4];
    #pragma unroll
    for (int i = 0; i < 4; ++i) acc[i] = (f32x4){0.f, 0.f, 0.f, 0.f};

    for (int kt = 0; kt < 44; ++kt) {
        int k0 = kt * 32 + q * 8;
        short8 af;
        if (kt == 43 && q == 3) {
            #pragma unroll
            for (int j = 0; j < 8; ++j) af[j] = 0;
        } else {
            f32x4 x0 = *(const f32x4*)(arow + k0);
            f32x4 x1 = *(const f32x4*)(arow + k0 + 4);
            #pragma unroll
            for (int j = 0; j < 4; ++j) { af[j] = (short)f2bf(x0[j]); af[4 + j] = (short)f2bf(x1[j]); }
        }
        #pragma unroll
        for (int i = 0; i < 4; ++i) {
            short8 bf = *(const short8*)(embT + (long)((ng + i) * 16 + l16) * VP_ + k0);
            acc[i] = __builtin_amdgcn_mfma_f32_16x16x32_bf16(af, bf, acc[i], 0, 0, 0);
        }
    }
    #pragma unroll
    for (int i = 0; i < 4; ++i) {
        int col = (ng + i) * 16 + l16;
        #pragma unroll
        for (int j = 0; j < 4; ++j) {
            int R = Rbase + 4 * q + j;
            embB[(long)R * H_ + col] = f2bf(acc[i][j]);
        }
    }
}

// ---------------------------------------------------------------- K2: P chunk = embedded @ [U1;U2]^T + bg
// (chunk-0 prologue and no-fuse fallback)
__global__ __launch_bounds__(512, 2) void k2_pre(const unsigned short* __restrict__ embB,
                                                 const unsigned short* __restrict__ Ub,
                                                 const float* __restrict__ bg,
                                                 float* __restrict__ P, int t0) {
    const int tid = threadIdx.x;
    const int w = tid >> 6, ln = tid & 63, q = ln >> 4, l16 = ln & 15;
    const int rbase = blockIdx.x * 32;  // local row' in chunk, 0..4095

    short8 af[2][8];
    #pragma unroll
    for (int mt = 0; mt < 2; ++mt)
        #pragma unroll
        for (int kt = 0; kt < 8; ++kt) {
            int rp = rbase + mt * 16 + l16;
            int rg = t0 * 64 + rp;
            int b = rg & 63, s = rg >> 6;
            af[mt][kt] = *(const short8*)(embB + ((long)b * S_ + s) * H_ + kt * 32 + q * 8);
        }

    for (int i = 0; i < 16; ++i) {
        int nt2 = w * 16 + i;          // global gate-col tile 0..127
        int l = nt2 >> 6;
        int gcol = (nt2 & 63) * 16 + l16;   // col within lstm, 0..1023
        float bias = bg[nt2 * 16 + l16];
        short8 bf[8];
        #pragma unroll
        for (int kt = 0; kt < 8; ++kt)
            bf[kt] = *(const short8*)(Ub + (long)(nt2 * 16 + l16) * H_ + kt * 32 + q * 8);
        #pragma unroll
        for (int mt = 0; mt < 2; ++mt) {
            f32x4 acc = (f32x4){bias, bias, bias, bias};
            #pragma unroll
            for (int kt = 0; kt < 8; ++kt)
                acc = __builtin_amdgcn_mfma_f32_16x16x32_bf16(af[mt][kt], bf[kt], acc, 0, 0, 0);
            int rp0 = rbase + mt * 16;
            float* dst = P + ((long)l * (CH_ * 64) + rp0 + 4 * q) * G4_ + gcol;
            #pragma unroll
            for (int j = 0; j < 4; ++j) dst[(long)j * G4_] = acc[j];
        }
    }
}

// ---------------------------------------------------------------- K3: fused LSTM chunk + next-chunk P GEMM
// Round-16: r7 base (best: 2822us) + minimum-transaction rendezvous.
//   10 rounds bracketed the rendezvous: the two fastest variants (r2 257,
//   r6/r7 270/273) differ from the slow ones mainly in SAME-LINE IC
//   transaction count; each serialized IC RMW is ~100-200cy, so r7's
//   16 posts + 16n poll-RMWs per step = 1.5-3us of pure contention.
//   This round: 4 posts + ~4-8 poll reads per step per cell —
//   POST: per-wave sc1-store drain (vmcnt0) -> __syncthreads -> tid0 posts
//         ONE fetch_add(+1) at AGENT scope (target 4t; r2-proven pattern).
//   POLL: tid0-only RMW(opaque 0) spin (r6-proven coherent), bounded;
//         block released via __syncthreads.
//   All else carried over unchanged from the proven set: sc1 gathers/stores,
//   pv ordered-asm staging vmcnt(24)/(16)/(0) (r10-validated), fused GEMM
//   role with double-buffered P, no XCD handshake (scope proven irrelevant).
__global__ __launch_bounds__(256, 1) void k3_fused(const float* __restrict__ ts,
                                                   const unsigned short* __restrict__ W, // Wg || Wd
                                                   const float* __restrict__ bd1,
                                                   const float* __restrict__ bd2,
                                                   const float* __restrict__ Pcur,
                                                   unsigned short* __restrict__ out1,
                                                   unsigned short* __restrict__ out2,
                                                   float* __restrict__ cst,
                                                   unsigned short* __restrict__ cx,
                                                   unsigned int* __restrict__ cnt,
                                                   int t0,
                                                   const unsigned short* __restrict__ embB,
                                                   const unsigned short* __restrict__ Ub,
                                                   const float* __restrict__ bg,
                                                   float* __restrict__ Pnext,
                                                   int next_t0) {
    const int tid = threadIdx.x;
    const int w = tid >> 6, ln = tid & 63, q = ln >> 4, l16 = ln & 15;
    const int bid = blockIdx.x;

    if (bid >= 32) {
        // ================= GEMM role: P(next chunk) = embB @ Ub^T + bg =======
        const int g2 = bid - 32;
        const int rbase = (g2 >> 1) * 32;
        const int hb = g2 & 1;

        short8 af[2][8];
        #pragma unroll
        for (int mt = 0; mt < 2; ++mt)
            #pragma unroll
            for (int kt = 0; kt < 8; ++kt) {
                int rp = rbase + mt * 16 + l16;
                int rg = next_t0 * 64 + rp;
                int b = rg & 63, s = rg >> 6;
                af[mt][kt] = *(const short8*)(embB + ((long)b * S_ + s) * H_ + kt * 32 + q * 8);
            }

        for (int i = 0; i < 16; ++i) {
            int nt2 = hb * 64 + w * 16 + i;
            int l = nt2 >> 6;
            int gcol = (nt2 & 63) * 16 + l16;
            float bias = bg[nt2 * 16 + l16];
            short8 bf[8];
            #pragma unroll
            for (int kt = 0; kt < 8; ++kt)
                bf[kt] = *(const short8*)(Ub + (long)(nt2 * 16 + l16) * H_ + kt * 32 + q * 8);
            #pragma unroll
            for (int mt = 0; mt < 2; ++mt) {
                f32x4 acc = (f32x4){bias, bias, bias, bias};
                #pragma unroll
                for (int kt = 0; kt < 8; ++kt)
                    acc = __builtin_amdgcn_mfma_f32_16x16x32_bf16(af[mt][kt], bf[kt], acc, 0, 0, 0);
                int rp0 = rbase + mt * 16;
                float* dst = Pnext + ((long)l * (CH_ * 64) + rp0 + 4 * q) * G4_ + gcol;
                #pragma unroll
                for (int j = 0; j < 4; ++j) dst[(long)j * G4_] = acc[j];
            }
        }
        return;
    }

    // ==================== LSTM role (blocks 0..31) ===========================
    __shared__ float ts_lds[16][CH_];    // 4 KB
    const int chunk = t0 >> 6;

    const int grp = bid & 7, cg = bid >> 3;
    const int l = grp >> 2, m = grp & 3, b0 = m * 16;
    const int hc0 = cg * 64 + w * 16;
    const int mycol = hc0 + l16;
    unsigned int* cell = cnt + (chunk * 8 + grp) * 64;
    unsigned short* outp = l ? out2 : out1;
    const float bdv = (l ? bd2 : bd1)[mycol];

    for (int i = tid; i < 16 * CH_; i += 256) {
        int r = i >> 6, cc = i & (CH_ - 1);
        ts_lds[r][cc] = ts[(b0 + r) * S_ + t0 + cc];
    }

    // -------- register/AGPR-resident weights (loaded once per launch) --------
    short8 wg[4][8];
    short8 wd[8];
    #pragma unroll
    for (int g = 0; g < 4; ++g)
        #pragma unroll
        for (int kt = 0; kt < 8; ++kt)
            wg[g][kt] = *(const short8*)(W + ((long)(l * G4_ + g * H_ + mycol)) * H_ + kt * 32 + q * 8);
    #pragma unroll
    for (int kt = 0; kt < 8; ++kt)
        wd[kt] = *(const short8*)(W + (long)2 * G4_ * H_ + ((long)(l * H_ + mycol)) * H_ + kt * 32 + q * 8);

    float cf[4];
    if (t0 == 0) {
        cf[0] = cf[1] = cf[2] = cf[3] = 0.f;
    } else {
        #pragma unroll
        for (int j = 0; j < 4; ++j)
            cf[j] = cst[(long)grp * 4096 + (4 * q + j) * 256 + mycol];
    }
    __syncthreads();   // ts_lds ready

    const float* Pbase = Pcur + ((long)l * (CH_ * 64) + b0) * G4_;
    unsigned opaque_zero;
    asm volatile("v_mov_b32 %0, 0" : "=v"(opaque_zero));

    #pragma unroll 1
    for (int t = 0; t < CH_; ++t) {
        const int gt = t0 + t;

        // 1. rendezvous: tid0-only bounded RMW poll (4 posts/step expected),
        //    block released by the barrier.
        if (t) {
            if (tid == 0) {
                const unsigned tgt = 4u * (unsigned)t;
                unsigned it = 0;
                for (;;) {
                    unsigned v = __hip_atomic_fetch_add(cell, opaque_zero,
                                                        __ATOMIC_RELAXED, __HIP_MEMORY_SCOPE_AGENT);
                    if (v >= tgt || ++it >= (1u << 15)) break;
                }
            }
            __syncthreads();
        }
        __builtin_amdgcn_sched_barrier(0);

        // 2. gathers (sc1) then pv (plain, ordered) -> staged vmcnt waits
        short8 ha[8], ca[8];
        if (gt == 0) {
            #pragma unroll
            for (int kt = 0; kt < 8; ++kt) {
                #pragma unroll
                for (int jj = 0; jj < 8; ++jj) { ha[kt][jj] = 0; ca[kt][jj] = 0; }
            }
        } else {
            const unsigned short* crow = cx + ((long)(((gt - 1) & 1) * 8 + grp)) * 4096 + l16 * 256 + q * 8;
            const unsigned short* hrow = outp + ((long)(b0 + l16) * S_ + (gt - 1)) * H_ + q * 8;
            #pragma unroll
            for (int kt = 0; kt < 8; ++kt) ca[kt] = gload16_sc1(crow + kt * 32);
            #pragma unroll
            for (int kt = 0; kt < 8; ++kt) ha[kt] = gload16_sc1(hrow + kt * 32);
        }
        float pv[4][4];
        #pragma unroll
        for (int g = 0; g < 4; ++g)
            #pragma unroll
            for (int j = 0; j < 4; ++j)
                pv[g][j] = gloadf_plain(Pbase + ((long)t * 64 + 4 * q + j) * G4_ + g * H_ + mycol);

        asm volatile("s_waitcnt vmcnt(24)" ::: "memory");   // ca complete
        __builtin_amdgcn_sched_barrier(0);
        f32x4 dacc = (f32x4){bdv, bdv, bdv, bdv};
        #pragma unroll
        for (int kt = 0; kt < 8; ++kt)
            dacc = __builtin_amdgcn_mfma_f32_16x16x32_bf16(ca[kt], wd[kt], dacc, 0, 0, 0);

        asm volatile("s_waitcnt vmcnt(16)" ::: "memory");   // ha complete
        __builtin_amdgcn_sched_barrier(0);
        f32x4 gacc[4];
        #pragma unroll
        for (int g = 0; g < 4; ++g) {
            gacc[g] = (f32x4){0.f, 0.f, 0.f, 0.f};
            #pragma unroll
            for (int kt = 0; kt < 8; ++kt)
                gacc[g] = __builtin_amdgcn_mfma_f32_16x16x32_bf16(ha[kt], wg[g][kt], gacc[g], 0, 0, 0);
        }

        asm volatile("s_waitcnt vmcnt(0)" ::: "memory");    // pv complete
        __builtin_amdgcn_sched_barrier(0);

        // 3. elementwise + sc1 stores
        #pragma unroll
        for (int j = 0; j < 4; ++j) {
            int r = 4 * q + j;
            float tv = ts_lds[r][t];
            float cs1 = ftanh(dacc[j]);
            float cadj = cf[j] + cs1 * (tv - 1.0f);
            float fg = fsig(gacc[0][j] + pv[0][j]);
            float ig = fsig(gacc[1][j] + pv[1][j]);
            float og = fsig(gacc[2][j] + pv[2][j]);
            float cg2 = fsig(gacc[3][j] + pv[3][j]);
            float cn = fg * cadj + ig * cg2;
            float hn = og * ftanh(cn);
            cf[j] = cn;
            gstore_short_sc1(outp + ((long)(b0 + r) * S_ + gt) * H_ + mycol, (unsigned)f2bf(hn));
            gstore_short_sc1(cx + ((long)((gt & 1) * 8 + grp)) * 4096 + r * 256 + mycol, (unsigned)f2bf(cn));
        }

        // 4. per-wave drain -> block barrier -> ONE post
        asm volatile("s_waitcnt vmcnt(0)" ::: "memory");
        __syncthreads();
        if (tid == 0)
            (void)__hip_atomic_fetch_add(cell, 1u, __ATOMIC_RELAXED, __HIP_MEMORY_SCOPE_AGENT);
    }

    // persist fp32 c for next chunk
    #pragma unroll
    for (int j = 0; j < 4; ++j)
        cst[(long)grp * 4096 + (4 * q + j) * 256 + mycol] = cf[j];
}

// ---------------------------------------------------------------- K4a: scores + softmax -> alpha
__global__ __launch_bounds__(512) void k4a_alpha(const unsigned short* __restrict__ out1,
                                                 const float* __restrict__ wa,
                                                 float* __restrict__ alpha) {
    __shared__ float sc[512];
    __shared__ float red[512];
    const int b = blockIdx.x, tid = threadIdx.x;
    const int w = tid >> 6, ln = tid & 63;
    f32x4 wv = *(const f32x4*)(wa + ln * 4);
    for (int i = 0; i < 64; ++i) {
        int s = w * 64 + i;
        const unsigned short* row = out1 + ((long)b * S_ + s) * H_ + ln * 4;
        float d = bf2f(row[0]) * wv[0] + bf2f(row[1]) * wv[1] +
                  bf2f(row[2]) * wv[2] + bf2f(row[3]) * wv[3];
        #pragma unroll
        for (int off = 32; off; off >>= 1) d += __shfl_xor(d, off);
        if (ln == 0) sc[s] = d;
    }
    __syncthreads();
    float v = sc[tid];
    red[tid] = v;
    for (int st = 256; st; st >>= 1) {
        __syncthreads();
        if (tid < st) red[tid] = fmaxf(red[tid], red[tid + st]);
    }
    __syncthreads();
    float M = red[0];
    __syncthreads();
    float e = __builtin_amdgcn_exp2f((v - M) * 1.44269504f);
    red[tid] = e;
    for (int st = 256; st; st >>= 1) {
        __syncthreads();
        if (tid < st) red[tid] += red[tid + st];
    }
    __syncthreads();
    alpha[b * S_ + tid] = e * __builtin_amdgcn_rcpf(red[0]);
}

// ---------------------------------------------------------------- K4b: Beta=tanh(out2@Wb^T); ctx = sum_s emb*Beta*alpha
__global__ __launch_bounds__(512, 2) void k4b_ctx(const unsigned short* __restrict__ out2,
                                                  const unsigned short* __restrict__ Wbb,
                                                  const unsigned short* __restrict__ embB,
                                                  const float* __restrict__ alpha,
                                                  float* __restrict__ ctx) {
    __shared__ float cbuf[32][256];
    const int b = blockIdx.x, tid = threadIdx.x;
    const int w = tid >> 6, ln = tid & 63, q = ln >> 4, l16 = ln & 15;

    float cp[16];
    #pragma unroll
    for (int nt = 0; nt < 16; ++nt) cp[nt] = 0.f;

    for (int i = 0; i < 4; ++i) {
        int mt = w * 4 + i;
        short8 af[8];
        #pragma unroll
        for (int kt = 0; kt < 8; ++kt)
            af[kt] = *(const short8*)(out2 + ((long)b * S_ + mt * 16 + l16) * H_ + kt * 32 + q * 8);
        float al[4];
        #pragma unroll
        for (int j = 0; j < 4; ++j) al[j] = alpha[b * S_ + mt * 16 + 4 * q + j];
        for (int nt = 0; nt < 16; ++nt) {
            f32x4 acc = (f32x4){0.f, 0.f, 0.f, 0.f};
            #pragma unroll
            for (int kt = 0; kt < 8; ++kt) {
                short8 bf = *(const short8*)(Wbb + (long)(nt * 16 + l16) * H_ + kt * 32 + q * 8);
                acc = __builtin_amdgcn_mfma_f32_16x16x32_bf16(af[kt], bf, acc, 0, 0, 0);
            }
            #pragma unroll
            for (int j = 0; j < 4; ++j) {
                int s = mt * 16 + 4 * q + j;
                float beta = ftanh(acc[j]);
                float ev = bf2f(embB[((long)b * S_ + s) * H_ + nt * 16 + l16]);
                cp[nt] += beta * al[j] * ev;
            }
        }
    }
    #pragma unroll
    for (int nt = 0; nt < 16; ++nt) cbuf[w * 4 + q][nt * 16 + l16] = cp[nt];
    __syncthreads();
    if (tid < 256) {
        float sum = 0.f;
        for (int i = 0; i < 32; ++i) sum += cbuf[i][tid];
        ctx[b * H_ + tid] = sum;
    }
}

// ---------------------------------------------------------------- K4c: out = ctx @ W_out^T
__global__ void k4c_out(const float* __restrict__ ctx, const float* __restrict__ Wout,
                        float* __restrict__ out) {
    int b = blockIdx.x, n = threadIdx.x;
    const f32x4* cr = (const f32x4*)(ctx + b * H_);
    const f32x4* wr = (const f32x4*)(Wout + n * H_);
    float acc = 0.f;
    #pragma unroll 8
    for (int i = 0; i < 64; ++i) {
        f32x4 c = cr[i], ww = wr[i];
        acc += c[0] * ww[0] + c[1] * ww[1] + c[2] * ww[2] + c[3] * ww[3];
    }
    out[b * NC_ + n] = acc;
}

// ---------------------------------------------------------------- launch
extern "C" void kernel_launch(void* const* d_in, const int* in_sizes, int n_in,
                              void* d_out, int out_size, void* d_ws, size_t ws_size,
                              hipStream_t stream) {
    (void)in_sizes; (void)n_in; (void)out_size;
    const float* inputs = (const float*)d_in[0];
    const float* tsp    = (const float*)d_in[1];
    const float* emb    = (const float*)d_in[2];
    const float* Wa1 = (const float*)d_in[3];  const float* ba1 = (const float*)d_in[4];
    const float* U1  = (const float*)d_in[5];  const float* bu1 = (const float*)d_in[6];
    const float* Wd1 = (const float*)d_in[7];  const float* bd1 = (const float*)d_in[8];
    const float* Wa2 = (const float*)d_in[9];  const float* ba2 = (const float*)d_in[10];
    const float* U2  = (const float*)d_in[11]; const float* bu2 = (const float*)d_in[12];
    const float* Wd2 = (const float*)d_in[13]; const float* bd2 = (const float*)d_in[14];
    const float* wa  = (const float*)d_in[15];
    const float* Wb  = (const float*)d_in[16];
    const float* Wout = (const float*)d_in[17];
    float* out = (float*)d_out;

    // Workspace map (round-16: layout as round-12/13).
    char* ws = (char*)d_ws;
    unsigned short* embT = (unsigned short*)(ws + 0);            //    720,896
    unsigned short* Wg   = (unsigned short*)(ws + 720896);       //  1,048,576 (Wd must follow)
    unsigned short* Wd   = (unsigned short*)(ws + 1769472);      //    262,144
    unsigned short* Ub   = (unsigned short*)(ws + 2031616);      //  1,048,576
    unsigned short* Wbb  = (unsigned short*)(ws + 3080192);      //    131,072
    float*          bgp  = (float*)(ws + 3211264);               //      8,192
    unsigned short* embB = (unsigned short*)(ws + 3219456);      // 16,777,216
    float*          P0   = (float*)(ws + 19996672);              // 33,554,432
    unsigned short* out1 = (unsigned short*)(ws + 53551104);     // 16,777,216
    unsigned short* out2 = (unsigned short*)(ws + 70328320);     // 16,777,216
    unsigned short* cx   = (unsigned short*)(ws + 87105536);     //    131,072
    float*          cst  = (float*)(ws + 87236608);              //    131,072
    float*          alp  = (float*)(ws + 87367680);              //    131,072
    float*          ctx  = (float*)(ws + 87498752);              //     65,536
    unsigned int*   cnt  = (unsigned int*)(ws + 87564288);       //    155,648
    float*          P1   = (float*)(ws + 87719936);              // 33,554,432 (fused path only)
    const size_t NEED_FUSED = 121274368;                         // 87,719,936 + 33,554,432
    const bool fuse = (ws_size >= NEED_FUSED);

    hipLaunchKernelGGL(k0_prep, dim3(256), dim3(256), 0, stream,
                       emb, Wa1, Wa2, Wd1, Wd2, U1, U2, ba1, bu1, ba2, bu2, Wb,
                       embT, Wg, Wd, Ub, Wbb, bgp, cnt);
    hipLaunchKernelGGL(k1_embed, dim3(1024), dim3(512), 0, stream, inputs, embT, embB);
    // prologue: P(chunk 0)
    hipLaunchKernelGGL(k2_pre, dim3(128), dim3(512), 0, stream, embB, Ub, bgp, P0, 0);

    float* Pb[2] = { P0, fuse ? P1 : P0 };
    for (int c = 0; c < 8; ++c) {
        if (fuse) {
            int ng = (c < 7) ? 256 : 0;
            hipLaunchKernelGGL(k3_fused, dim3(32 + ng), dim3(256), 0, stream,
                               tsp, Wg, bd1, bd2, Pb[c & 1], out1, out2, cst, cx, cnt, c * CH_,
                               embB, Ub, bgp, Pb[(c + 1) & 1], (c + 1) * CH_);
        } else {
            if (c > 0)
                hipLaunchKernelGGL(k2_pre, dim3(128), dim3(512), 0, stream, embB, Ub, bgp, P0, c * CH_);
            hipLaunchKernelGGL(k3_fused, dim3(32), dim3(256), 0, stream,
                               tsp, Wg, bd1, bd2, P0, out1, out2, cst, cx, cnt, c * CH_,
                               embB, Ub, bgp, P0, S_ /* unused: no GEMM blocks */);
        }
    }
    hipLaunchKernelGGL(k4a_alpha, dim3(64), dim3(512), 0, stream, out1, wa, alp);
    hipLaunchKernelGGL(k4b_ctx, dim3(64), dim3(512), 0, stream, out2, Wbb, embB, alp, ctx);
    hipLaunchKernelGGL(k4c_out, dim3(64), dim3(128), 0, stream, ctx, Wout, out);
}

// Round 13
// 2833.892 us; speedup vs baseline: 2.4048x; 1.0026x over previous
//
#include <hip/hip_runtime.h>

typedef __attribute__((ext_vector_type(8))) short short8;
typedef __attribute__((ext_vector_type(4))) float f32x4;

#define B_   64
#define S_   512
#define V_   1400
#define VP_  1408
#define H_   256
#define G4_  1024
#define NC_  128
#define CH_  64    // time-chunk length (8 chunks of 64 steps)

__device__ __forceinline__ unsigned short f2bf(float f) {
    unsigned u = __builtin_bit_cast(unsigned, f);
    u += 0x7FFFu + ((u >> 16) & 1u);
    return (unsigned short)(u >> 16);
}
__device__ __forceinline__ float bf2f(unsigned short h) {
    unsigned u = ((unsigned)h) << 16;
    return __builtin_bit_cast(float, u);
}
__device__ __forceinline__ float fsig(float x) {
    x = fminf(fmaxf(x, -40.f), 40.f);
    float e = __builtin_amdgcn_exp2f(x * -1.44269504f);
    return __builtin_amdgcn_rcpf(1.0f + e);
}
__device__ __forceinline__ float ftanh(float x) {
    x = fminf(fmaxf(x, -40.f), 40.f);
    float e = __builtin_amdgcn_exp2f(x * 2.88539008f);
    return 1.0f - 2.0f * __builtin_amdgcn_rcpf(e + 1.0f);
}

// ---- IC-coherent data primitives (proven r2/r7/r11) ----
__device__ __forceinline__ short8 gload16_sc1(const unsigned short* p) {
    short8 r;
    asm volatile("global_load_dwordx4 %0, %1, off sc1"
                 : "=&v"(r) : "v"((unsigned long long)p));
    return r;
}
__device__ __forceinline__ void gstore_short_sc1(unsigned short* p, unsigned v) {
    asm volatile("global_store_short %0, %1, off sc1"
                 :: "v"((unsigned long long)p), "v"(v));
}
// plain dword load via asm — ordered among the volatile-asm vmem stream so the
// staged vmcnt(24)/(16)/(0) counts are exact (r10/r11-validated bit-correct).
__device__ __forceinline__ float gloadf_plain(const float* p) {
    float r;
    asm volatile("global_load_dword %0, %1, off"
                 : "=&v"(r) : "v"((unsigned long long)p));
    return r;
}

// cnt zone (ints): chain cells at (chunk*8+grp)*64, 256B-spaced  [0,4096)
#define CNT_ZONE_ 4096

// ---------------------------------------------------------------- K0: prep
__global__ void k0_prep(const float* __restrict__ emb,
                        const float* __restrict__ Wa1, const float* __restrict__ Wa2,
                        const float* __restrict__ Wd1, const float* __restrict__ Wd2,
                        const float* __restrict__ U1,  const float* __restrict__ U2,
                        const float* __restrict__ ba1, const float* __restrict__ bu1,
                        const float* __restrict__ ba2, const float* __restrict__ bu2,
                        const float* __restrict__ Wb,
                        unsigned short* __restrict__ embT, unsigned short* __restrict__ Wg,
                        unsigned short* __restrict__ Wd,   unsigned short* __restrict__ Ub,
                        unsigned short* __restrict__ Wbb,  float* __restrict__ bg,
                        unsigned int* __restrict__ cnt) {
    int tid = blockIdx.x * blockDim.x + threadIdx.x;
    int np = gridDim.x * blockDim.x;
    for (int i = tid; i < 256 * VP_; i += np) {
        int n = i / VP_, k = i - n * VP_;
        embT[i] = (k < V_) ? f2bf(emb[k * H_ + n]) : (unsigned short)0;
    }
    for (int i = tid; i < G4_ * H_; i += np) {
        Wg[i] = f2bf(Wa1[i]); Wg[G4_ * H_ + i] = f2bf(Wa2[i]);
        Ub[i] = f2bf(U1[i]);  Ub[G4_ * H_ + i] = f2bf(U2[i]);
    }
    for (int i = tid; i < H_ * H_; i += np) {
        Wd[i] = f2bf(Wd1[i]); Wd[H_ * H_ + i] = f2bf(Wd2[i]); Wbb[i] = f2bf(Wb[i]);
    }
    for (int i = tid; i < G4_; i += np) {
        bg[i] = ba1[i] + bu1[i]; bg[G4_ + i] = ba2[i] + bu2[i];
    }
    for (int i = tid; i < CNT_ZONE_; i += np) cnt[i] = 0;   // chain cells, re-zeroed every run
}

// ---------------------------------------------------------------- K1: embedded = inputs @ emb
__global__ __launch_bounds__(512, 2) void k1_embed(const float* __restrict__ inputs,
                                                   const unsigned short* __restrict__ embT,
                                                   unsigned short* __restrict__ embB) {
    const int tid = threadIdx.x;
    const int w = tid >> 6, ln = tid & 63, q = ln >> 4, l16 = ln & 15;
    const int mt = w >> 2, ng = (w & 3) * 4;
    const int Rbase = blockIdx.x * 32 + mt * 16;
    const float* arow = inputs + (long)(Rbase + l16) * V_;

    f32x4 acc[4];
    #pragma unroll
    for (int i = 0; i < 4; ++i) acc[i] = (f32x4){0.f, 0.f, 0.f, 0.f};

    for (int kt = 0; kt < 44; ++kt) {
        int k0 = kt * 32 + q * 8;
        short8 af;
        if (kt == 43 && q == 3) {
            #pragma unroll
            for (int j = 0; j < 8; ++j) af[j] = 0;
        } else {
            f32x4 x0 = *(const f32x4*)(arow + k0);
            f32x4 x1 = *(const f32x4*)(arow + k0 + 4);
            #pragma unroll
            for (int j = 0; j < 4; ++j) { af[j] = (short)f2bf(x0[j]); af[4 + j] = (short)f2bf(x1[j]); }
        }
        #pragma unroll
        for (int i = 0; i < 4; ++i) {
            short8 bf = *(const short8*)(embT + (long)((ng + i) * 16 + l16) * VP_ + k0);
            acc[i] = __builtin_amdgcn_mfma_f32_16x16x32_bf16(af, bf, acc[i], 0, 0, 0);
        }
    }
    #pragma unroll
    for (int i = 0; i < 4; ++i) {
        int col = (ng + i) * 16 + l16;
        #pragma unroll
        for (int j = 0; j < 4; ++j) {
            int R = Rbase + 4 * q + j;
            embB[(long)R * H_ + col] = f2bf(acc[i][j]);
        }
    }
}

// ---------------------------------------------------------------- K2: P chunk = embedded @ [U1;U2]^T + bg
// (chunk-0 prologue and no-fuse fallback)
__global__ __launch_bounds__(512, 2) void k2_pre(const unsigned short* __restrict__ embB,
                                                 const unsigned short* __restrict__ Ub,
                                                 const float* __restrict__ bg,
                                                 float* __restrict__ P, int t0) {
    const int tid = threadIdx.x;
    const int w = tid >> 6, ln = tid & 63, q = ln >> 4, l16 = ln & 15;
    const int rbase = blockIdx.x * 32;  // local row' in chunk, 0..4095

    short8 af[2][8];
    #pragma unroll
    for (int mt = 0; mt < 2; ++mt)
        #pragma unroll
        for (int kt = 0; kt < 8; ++kt) {
            int rp = rbase + mt * 16 + l16;
            int rg = t0 * 64 + rp;
            int b = rg & 63, s = rg >> 6;
            af[mt][kt] = *(const short8*)(embB + ((long)b * S_ + s) * H_ + kt * 32 + q * 8);
        }

    for (int i = 0; i < 16; ++i) {
        int nt2 = w * 16 + i;          // global gate-col tile 0..127
        int l = nt2 >> 6;
        int gcol = (nt2 & 63) * 16 + l16;   // col within lstm, 0..1023
        float bias = bg[nt2 * 16 + l16];
        short8 bf[8];
        #pragma unroll
        for (int kt = 0; kt < 8; ++kt)
            bf[kt] = *(const short8*)(Ub + (long)(nt2 * 16 + l16) * H_ + kt * 32 + q * 8);
        #pragma unroll
        for (int mt = 0; mt < 2; ++mt) {
            f32x4 acc = (f32x4){bias, bias, bias, bias};
            #pragma unroll
            for (int kt = 0; kt < 8; ++kt)
                acc = __builtin_amdgcn_mfma_f32_16x16x32_bf16(af[mt][kt], bf[kt], acc, 0, 0, 0);
            int rp0 = rbase + mt * 16;
            float* dst = P + ((long)l * (CH_ * 64) + rp0 + 4 * q) * G4_ + gcol;
            #pragma unroll
            for (int j = 0; j < 4; ++j) dst[(long)j * G4_] = acc[j];
        }
    }
}

// ---------------------------------------------------------------- K3: fused LSTM chunk + next-chunk P GEMM
// Round-18: byte-identical to the round-16/r11 kernel (proven passing, k3 at
// its bracketed floor of ~276us/dispatch). 12 rounds established the per-step
// rendezvous (~4.2us) is a fixed IC-latency chain, invariant under detection
// primitive, scope, topology, and transaction count. No k3 changes this round.
__global__ __launch_bounds__(256, 1) void k3_fused(const float* __restrict__ ts,
                                                   const unsigned short* __restrict__ W, // Wg || Wd
                                                   const float* __restrict__ bd1,
                                                   const float* __restrict__ bd2,
                                                   const float* __restrict__ Pcur,
                                                   unsigned short* __restrict__ out1,
                                                   unsigned short* __restrict__ out2,
                                                   float* __restrict__ cst,
                                                   unsigned short* __restrict__ cx,
                                                   unsigned int* __restrict__ cnt,
                                                   int t0,
                                                   const unsigned short* __restrict__ embB,
                                                   const unsigned short* __restrict__ Ub,
                                                   const float* __restrict__ bg,
                                                   float* __restrict__ Pnext,
                                                   int next_t0) {
    const int tid = threadIdx.x;
    const int w = tid >> 6, ln = tid & 63, q = ln >> 4, l16 = ln & 15;
    const int bid = blockIdx.x;

    if (bid >= 32) {
        // ================= GEMM role: P(next chunk) = embB @ Ub^T + bg =======
        const int g2 = bid - 32;
        const int rbase = (g2 >> 1) * 32;
        const int hb = g2 & 1;

        short8 af[2][8];
        #pragma unroll
        for (int mt = 0; mt < 2; ++mt)
            #pragma unroll
            for (int kt = 0; kt < 8; ++kt) {
                int rp = rbase + mt * 16 + l16;
                int rg = next_t0 * 64 + rp;
                int b = rg & 63, s = rg >> 6;
                af[mt][kt] = *(const short8*)(embB + ((long)b * S_ + s) * H_ + kt * 32 + q * 8);
            }

        for (int i = 0; i < 16; ++i) {
            int nt2 = hb * 64 + w * 16 + i;
            int l = nt2 >> 6;
            int gcol = (nt2 & 63) * 16 + l16;
            float bias = bg[nt2 * 16 + l16];
            short8 bf[8];
            #pragma unroll
            for (int kt = 0; kt < 8; ++kt)
                bf[kt] = *(const short8*)(Ub + (long)(nt2 * 16 + l16) * H_ + kt * 32 + q * 8);
            #pragma unroll
            for (int mt = 0; mt < 2; ++mt) {
                f32x4 acc = (f32x4){bias, bias, bias, bias};
                #pragma unroll
                for (int kt = 0; kt < 8; ++kt)
                    acc = __builtin_amdgcn_mfma_f32_16x16x32_bf16(af[mt][kt], bf[kt], acc, 0, 0, 0);
                int rp0 = rbase + mt * 16;
                float* dst = Pnext + ((long)l * (CH_ * 64) + rp0 + 4 * q) * G4_ + gcol;
                #pragma unroll
                for (int j = 0; j < 4; ++j) dst[(long)j * G4_] = acc[j];
            }
        }
        return;
    }

    // ==================== LSTM role (blocks 0..31) ===========================
    __shared__ float ts_lds[16][CH_];    // 4 KB

    const int chunk = t0 >> 6;
    const int grp = bid & 7, cg = bid >> 3;
    const int l = grp >> 2, m = grp & 3, b0 = m * 16;
    const int hc0 = cg * 64 + w * 16;
    const int mycol = hc0 + l16;
    unsigned int* cell = cnt + (chunk * 8 + grp) * 64;
    unsigned short* outp = l ? out2 : out1;
    const float bdv = (l ? bd2 : bd1)[mycol];

    for (int i = tid; i < 16 * CH_; i += 256) {
        int r = i >> 6, cc = i & (CH_ - 1);
        ts_lds[r][cc] = ts[(b0 + r) * S_ + t0 + cc];
    }

    // -------- register/AGPR-resident weights (loaded once per launch) --------
    short8 wg[4][8];
    short8 wd[8];
    #pragma unroll
    for (int g = 0; g < 4; ++g)
        #pragma unroll
        for (int kt = 0; kt < 8; ++kt)
            wg[g][kt] = *(const short8*)(W + ((long)(l * G4_ + g * H_ + mycol)) * H_ + kt * 32 + q * 8);
    #pragma unroll
    for (int kt = 0; kt < 8; ++kt)
        wd[kt] = *(const short8*)(W + (long)2 * G4_ * H_ + ((long)(l * H_ + mycol)) * H_ + kt * 32 + q * 8);

    float cf[4];
    if (t0 == 0) {
        cf[0] = cf[1] = cf[2] = cf[3] = 0.f;
    } else {
        #pragma unroll
        for (int j = 0; j < 4; ++j)
            cf[j] = cst[(long)grp * 4096 + (4 * q + j) * 256 + mycol];
    }
    __syncthreads();   // ts_lds ready

    const float* Pbase = Pcur + ((long)l * (CH_ * 64) + b0) * G4_;
    unsigned opaque_zero;
    asm volatile("v_mov_b32 %0, 0" : "=v"(opaque_zero));

    #pragma unroll 1
    for (int t = 0; t < CH_; ++t) {
        const int gt = t0 + t;

        // 1. rendezvous: tid0-only bounded RMW poll; block released by barrier.
        if (t) {
            if (tid == 0) {
                const unsigned tgt = 4u * (unsigned)t;
                unsigned it = 0;
                for (;;) {
                    unsigned v = __hip_atomic_fetch_add(cell, opaque_zero,
                                                        __ATOMIC_RELAXED, __HIP_MEMORY_SCOPE_AGENT);
                    if (v >= tgt || ++it >= (1u << 15)) break;
                }
            }
            __syncthreads();
        }
        __builtin_amdgcn_sched_barrier(0);

        // 2. gathers (sc1) then pv (plain, ordered) -> staged vmcnt waits
        short8 ha[8], ca[8];
        if (gt == 0) {
            #pragma unroll
            for (int kt = 0; kt < 8; ++kt) {
                #pragma unroll
                for (int jj = 0; jj < 8; ++jj) { ha[kt][jj] = 0; ca[kt][jj] = 0; }
            }
        } else {
            const unsigned short* crow = cx + ((long)(((gt - 1) & 1) * 8 + grp)) * 4096 + l16 * 256 + q * 8;
            const unsigned short* hrow = outp + ((long)(b0 + l16) * S_ + (gt - 1)) * H_ + q * 8;
            #pragma unroll
            for (int kt = 0; kt < 8; ++kt) ca[kt] = gload16_sc1(crow + kt * 32);
            #pragma unroll
            for (int kt = 0; kt < 8; ++kt) ha[kt] = gload16_sc1(hrow + kt * 32);
        }
        float pv[4][4];
        #pragma unroll
        for (int g = 0; g < 4; ++g)
            #pragma unroll
            for (int j = 0; j < 4; ++j)
                pv[g][j] = gloadf_plain(Pbase + ((long)t * 64 + 4 * q + j) * G4_ + g * H_ + mycol);

        asm volatile("s_waitcnt vmcnt(24)" ::: "memory");   // ca complete
        __builtin_amdgcn_sched_barrier(0);
        f32x4 dacc = (f32x4){bdv, bdv, bdv, bdv};
        #pragma unroll
        for (int kt = 0; kt < 8; ++kt)
            dacc = __builtin_amdgcn_mfma_f32_16x16x32_bf16(ca[kt], wd[kt], dacc, 0, 0, 0);

        asm volatile("s_waitcnt vmcnt(16)" ::: "memory");   // ha complete
        __builtin_amdgcn_sched_barrier(0);
        f32x4 gacc[4];
        #pragma unroll
        for (int g = 0; g < 4; ++g) {
            gacc[g] = (f32x4){0.f, 0.f, 0.f, 0.f};
            #pragma unroll
            for (int kt = 0; kt < 8; ++kt)
                gacc[g] = __builtin_amdgcn_mfma_f32_16x16x32_bf16(ha[kt], wg[g][kt], gacc[g], 0, 0, 0);
        }

        asm volatile("s_waitcnt vmcnt(0)" ::: "memory");    // pv complete
        __builtin_amdgcn_sched_barrier(0);

        // 3. elementwise + sc1 stores
        #pragma unroll
        for (int j = 0; j < 4; ++j) {
            int r = 4 * q + j;
            float tv = ts_lds[r][t];
            float cs1 = ftanh(dacc[j]);
            float cadj = cf[j] + cs1 * (tv - 1.0f);
            float fg = fsig(gacc[0][j] + pv[0][j]);
            float ig = fsig(gacc[1][j] + pv[1][j]);
            float og = fsig(gacc[2][j] + pv[2][j]);
            float cg2 = fsig(gacc[3][j] + pv[3][j]);
            float cn = fg * cadj + ig * cg2;
            float hn = og * ftanh(cn);
            cf[j] = cn;
            gstore_short_sc1(outp + ((long)(b0 + r) * S_ + gt) * H_ + mycol, (unsigned)f2bf(hn));
            gstore_short_sc1(cx + ((long)((gt & 1) * 8 + grp)) * 4096 + r * 256 + mycol, (unsigned)f2bf(cn));
        }

        // 4. per-wave drain -> block barrier -> ONE post
        asm volatile("s_waitcnt vmcnt(0)" ::: "memory");
        __syncthreads();
        if (tid == 0)
            (void)__hip_atomic_fetch_add(cell, 1u, __ATOMIC_RELAXED, __HIP_MEMORY_SCOPE_AGENT);
    }

    // persist fp32 c for next chunk
    #pragma unroll
    for (int j = 0; j < 4; ++j)
        cst[(long)grp * 4096 + (4 * q + j) * 256 + mycol] = cf[j];
}

// ---------------------------------------------------------------- K4: fused alpha + Beta/ctx + out
// Round-18: k4a+k4b+k4c merged per batch-row block. alpha and ctx never leave
// LDS (removes 2 launches + 2 global produce-consume round trips). Numerics
// identical: same score/softmax arithmetic, same MFMA tiling, same dot order.
__global__ __launch_bounds__(512, 2) void k4_all(const unsigned short* __restrict__ out1,
                                                 const unsigned short* __restrict__ out2,
                                                 const unsigned short* __restrict__ Wbb,
                                                 const unsigned short* __restrict__ embB,
                                                 const float* __restrict__ wa,
                                                 const float* __restrict__ Wout,
                                                 float* __restrict__ out) {
    __shared__ float sc[512];
    __shared__ float red[512];
    __shared__ float alp_l[512];
    __shared__ float cbuf[32][256];
    __shared__ float ctx_l[256];
    const int b = blockIdx.x, tid = threadIdx.x;
    const int w = tid >> 6, ln = tid & 63, q = ln >> 4, l16 = ln & 15;

    // -------- phase A: scores + softmax (was k4a) --------
    f32x4 wv = *(const f32x4*)(wa + ln * 4);
    for (int i = 0; i < 64; ++i) {
        int s = w * 64 + i;
        const unsigned short* row = out1 + ((long)b * S_ + s) * H_ + ln * 4;
        float d = bf2f(row[0]) * wv[0] + bf2f(row[1]) * wv[1] +
                  bf2f(row[2]) * wv[2] + bf2f(row[3]) * wv[3];
        #pragma unroll
        for (int off = 32; off; off >>= 1) d += __shfl_xor(d, off);
        if (ln == 0) sc[s] = d;
    }
    __syncthreads();
    float v = sc[tid];
    red[tid] = v;
    for (int st = 256; st; st >>= 1) {
        __syncthreads();
        if (tid < st) red[tid] = fmaxf(red[tid], red[tid + st]);
    }
    __syncthreads();
    float M = red[0];
    __syncthreads();
    float e = __builtin_amdgcn_exp2f((v - M) * 1.44269504f);
    red[tid] = e;
    for (int st = 256; st; st >>= 1) {
        __syncthreads();
        if (tid < st) red[tid] += red[tid + st];
    }
    __syncthreads();
    alp_l[tid] = e * __builtin_amdgcn_rcpf(red[0]);
    __syncthreads();

    // -------- phase B: Beta = tanh(out2 @ Wb^T); ctx accumulation (was k4b) --
    float cp[16];
    #pragma unroll
    for (int nt = 0; nt < 16; ++nt) cp[nt] = 0.f;

    for (int i = 0; i < 4; ++i) {
        int mt = w * 4 + i;
        short8 af[8];
        #pragma unroll
        for (int kt = 0; kt < 8; ++kt)
            af[kt] = *(const short8*)(out2 + ((long)b * S_ + mt * 16 + l16) * H_ + kt * 32 + q * 8);
        float al[4];
        #pragma unroll
        for (int j = 0; j < 4; ++j) al[j] = alp_l[mt * 16 + 4 * q + j];
        for (int nt = 0; nt < 16; ++nt) {
            f32x4 acc = (f32x4){0.f, 0.f, 0.f, 0.f};
            #pragma unroll
            for (int kt = 0; kt < 8; ++kt) {
                short8 bf = *(const short8*)(Wbb + (long)(nt * 16 + l16) * H_ + kt * 32 + q * 8);
                acc = __builtin_amdgcn_mfma_f32_16x16x32_bf16(af[kt], bf, acc, 0, 0, 0);
            }
            #pragma unroll
            for (int j = 0; j < 4; ++j) {
                int s = mt * 16 + 4 * q + j;
                float beta = ftanh(acc[j]);
                float ev = bf2f(embB[((long)b * S_ + s) * H_ + nt * 16 + l16]);
                cp[nt] += beta * al[j] * ev;
            }
        }
    }
    #pragma unroll
    for (int nt = 0; nt < 16; ++nt) cbuf[w * 4 + q][nt * 16 + l16] = cp[nt];
    __syncthreads();
    if (tid < 256) {
        float sum = 0.f;
        for (int i = 0; i < 32; ++i) sum += cbuf[i][tid];
        ctx_l[tid] = sum;
    }
    __syncthreads();

    // -------- phase C: out = ctx @ W_out^T (was k4c) --------
    if (tid < NC_) {
        const float* cr = ctx_l;
        const f32x4* wr = (const f32x4*)(Wout + tid * H_);
        float acc = 0.f;
        #pragma unroll 8
        for (int i = 0; i < 64; ++i) {
            f32x4 ww = wr[i];
            acc += cr[4 * i] * ww[0] + cr[4 * i + 1] * ww[1] +
                   cr[4 * i + 2] * ww[2] + cr[4 * i + 3] * ww[3];
        }
        out[b * NC_ + tid] = acc;
    }
}

// ---------------------------------------------------------------- launch
extern "C" void kernel_launch(void* const* d_in, const int* in_sizes, int n_in,
                              void* d_out, int out_size, void* d_ws, size_t ws_size,
                              hipStream_t stream) {
    (void)in_sizes; (void)n_in; (void)out_size;
    const float* inputs = (const float*)d_in[0];
    const float* tsp    = (const float*)d_in[1];
    const float* emb    = (const float*)d_in[2];
    const float* Wa1 = (const float*)d_in[3];  const float* ba1 = (const float*)d_in[4];
    const float* U1  = (const float*)d_in[5];  const float* bu1 = (const float*)d_in[6];
    const float* Wd1 = (const float*)d_in[7];  const float* bd1 = (const float*)d_in[8];
    const float* Wa2 = (const float*)d_in[9];  const float* ba2 = (const float*)d_in[10];
    const float* U2  = (const float*)d_in[11]; const float* bu2 = (const float*)d_in[12];
    const float* Wd2 = (const float*)d_in[13]; const float* bd2 = (const float*)d_in[14];
    const float* wa  = (const float*)d_in[15];
    const float* Wb  = (const float*)d_in[16];
    const float* Wout = (const float*)d_in[17];
    float* out = (float*)d_out;

    // Workspace map (round-18: identical to round-16/r11 layout).
    char* ws = (char*)d_ws;
    unsigned short* embT = (unsigned short*)(ws + 0);            //    720,896
    unsigned short* Wg   = (unsigned short*)(ws + 720896);       //  1,048,576 (Wd must follow)
    unsigned short* Wd   = (unsigned short*)(ws + 1769472);      //    262,144
    unsigned short* Ub   = (unsigned short*)(ws + 2031616);      //  1,048,576
    unsigned short* Wbb  = (unsigned short*)(ws + 3080192);      //    131,072
    float*          bgp  = (float*)(ws + 3211264);               //      8,192
    unsigned short* embB = (unsigned short*)(ws + 3219456);      // 16,777,216
    float*          P0   = (float*)(ws + 19996672);              // 33,554,432
    unsigned short* out1 = (unsigned short*)(ws + 53551104);     // 16,777,216
    unsigned short* out2 = (unsigned short*)(ws + 70328320);     // 16,777,216
    unsigned short* cx   = (unsigned short*)(ws + 87105536);     //    131,072
    float*          cst  = (float*)(ws + 87236608);              //    131,072
    unsigned int*   cnt  = (unsigned int*)(ws + 87564288);       //    155,648
    float*          P1   = (float*)(ws + 87719936);              // 33,554,432 (fused path only)
    const size_t NEED_FUSED = 121274368;                         // 87,719,936 + 33,554,432
    const bool fuse = (ws_size >= NEED_FUSED);

    hipLaunchKernelGGL(k0_prep, dim3(256), dim3(256), 0, stream,
                       emb, Wa1, Wa2, Wd1, Wd2, U1, U2, ba1, bu1, ba2, bu2, Wb,
                       embT, Wg, Wd, Ub, Wbb, bgp, cnt);
    hipLaunchKernelGGL(k1_embed, dim3(1024), dim3(512), 0, stream, inputs, embT, embB);
    // prologue: P(chunk 0)
    hipLaunchKernelGGL(k2_pre, dim3(128), dim3(512), 0, stream, embB, Ub, bgp, P0, 0);

    float* Pb[2] = { P0, fuse ? P1 : P0 };
    for (int c = 0; c < 8; ++c) {
        if (fuse) {
            int ng = (c < 7) ? 256 : 0;
            hipLaunchKernelGGL(k3_fused, dim3(32 + ng), dim3(256), 0, stream,
                               tsp, Wg, bd1, bd2, Pb[c & 1], out1, out2, cst, cx, cnt, c * CH_,
                               embB, Ub, bgp, Pb[(c + 1) & 1], (c + 1) * CH_);
        } else {
            if (c > 0)
                hipLaunchKernelGGL(k2_pre, dim3(128), dim3(512), 0, stream, embB, Ub, bgp, P0, c * CH_);
            hipLaunchKernelGGL(k3_fused, dim3(32), dim3(256), 0, stream,
                               tsp, Wg, bd1, bd2, P0, out1, out2, cst, cx, cnt, c * CH_,
                               embB, Ub, bgp, P0, S_ /* unused: no GEMM blocks */);
        }
    }
    hipLaunchKernelGGL(k4_all, dim3(64), dim3(512), 0, stream,
                       out1, out2, Wbb, embB, wa, Wout, out);
}